// Round 5
// baseline (11031.609 us; speedup 1.0000x reference)
//
#include <hip/hip_runtime.h>

#define N_TOK 32768
#define DIM   256
#define KCB   4096
#define MROWS 64           // rows per block
#define XSP   260          // padded xstage row stride (floats)
#define NTILE (KCB / 16)   // 256 code-tiles of 16 codes
#define TILE_B 8448        // 16*256*2 (bf16, swizzled) + 256 (C floats, 64B valid)
// ---- legacy-kernel tile params (fallback path) ----
#define KT    256
#define NKT   (KCB / KT)
#define DC    8
#define NDC   (DIM / DC)
#define ESD   258

// ws layout (bytes):
//   0      : double lossAcc (zeroed by 16B memset)
//   16     : float A[N_TOK]  -- numpy-replica fp32 ||x_i||^2
//   131088 : float C[KCB]    -- fp32 ||e_k||^2
//   147472 : etiles[256][8448] -- pre-swizzled bf16 code-tiles + appended C
#define WS_A 16
#define WS_C (16 + 4 * N_TOK)
#define WS_E (WS_C + 4 * KCB)
#define WS_NEED_NEW ((size_t)WS_E + (size_t)NTILE * TILE_B)

#define CAP    32          // candidate list capacity per row
#define MARGIN 1.5e-3f     // > 2x worst-case bf16-approx error bound (~7e-4)

typedef __attribute__((ext_vector_type(8))) short short8v;  // 8 x bf16 bits
typedef __attribute__((ext_vector_type(4))) float f32x4;

__device__ __forceinline__ unsigned short f2bf_rne(float f) {
    unsigned u = __float_as_uint(f);
    unsigned r = (u + 0x7FFFu + ((u >> 16) & 1u)) >> 16;
    return (unsigned short)r;
}

// async global->LDS staging helpers (size must be literal)
__device__ __forceinline__ void gld16(const void* g, void* l) {
    __builtin_amdgcn_global_load_lds(
        (const __attribute__((address_space(1))) unsigned int*)g,
        (__attribute__((address_space(3))) unsigned int*)l, 16, 0, 0);
}
__device__ __forceinline__ void gld4(const void* g, void* l) {
    __builtin_amdgcn_global_load_lds(
        (const __attribute__((address_space(1))) unsigned int*)g,
        (__attribute__((address_space(3))) unsigned int*)l, 4, 0, 0);
}

// ---------------------------------------------------------------------------
// Kernel A: bit-exact replica of numpy's fp32 pairwise row sum-of-squares.
__global__ __launch_bounds__(256) void xsq_np_kernel(const float* __restrict__ x,
                                                     float* __restrict__ A) {
#pragma clang fp contract(off)
    __shared__ float xr[4][256];
    const int tid = threadIdx.x;
    const int w = tid >> 6, l = tid & 63;
    const int row = blockIdx.x * 4 + w;
    float4 v = *(const float4*)(x + (size_t)row * DIM + l * 4);
    xr[w][l * 4 + 0] = v.x; xr[w][l * 4 + 1] = v.y;
    xr[w][l * 4 + 2] = v.z; xr[w][l * 4 + 3] = v.w;
    __syncthreads();
    const float* t = xr[w];
    const int g = (l >> 4) & 1;
    const int j = l & 15;
    const int base = g * 128 + j;
    float t0 = t[base +   0] * t[base +   0];
    float t1 = t[base +  16] * t[base +  16];
    float t2 = t[base +  32] * t[base +  32];
    float t3 = t[base +  48] * t[base +  48];
    float t4 = t[base +  64] * t[base +  64];
    float t5 = t[base +  80] * t[base +  80];
    float t6 = t[base +  96] * t[base +  96];
    float t7 = t[base + 112] * t[base + 112];
    float p = ((t0 + t1) + (t2 + t3)) + ((t4 + t5) + (t6 + t7));
    p = p + __shfl_xor(p, 8, 64);
    p = p + __shfl_xor(p, 4, 64);
    p = p + __shfl_xor(p, 2, 64);
    p = p + __shfl_xor(p, 1, 64);
    float other = __shfl(p, 16, 64);
    if (l == 0) A[row] = p + other;
}

// ---------------------------------------------------------------------------
// Kernel B: C[k] exact; also emits PRE-SWIZZLED bf16 tiles + appended C.
// Rotation swizzle: 16B unit u stored at u ^ f(jj), f(jj)=((jj>>1)&3)|((jj&1)<<2).
__global__ void esq_np_kernel(const float* __restrict__ emb, float* __restrict__ C,
                              unsigned char* __restrict__ etiles) {
#pragma clang fp contract(off)
    int row  = blockIdx.x * 4 + (threadIdx.x >> 6);
    int lane = threadIdx.x & 63;
    float4 v = *(const float4*)(emb + (size_t)row * DIM + lane * 4);
    int tile = row >> 4, jj = row & 15;
    if (etiles) {
        ushort4 h;
        h.x = f2bf_rne(v.x); h.y = f2bf_rne(v.y);
        h.z = f2bf_rne(v.z); h.w = f2bf_rne(v.w);
        int f  = ((jj >> 1) & 3) | ((jj & 1) << 2);
        int u  = jj * 32 + (lane >> 1);      // 16B unit within tile
        int qs = u ^ f;                      // swizzled unit (stays in row: f<8<32)
        *(ushort4*)(etiles + (size_t)tile * TILE_B + qs * 16 + (lane & 1) * 8) = h;
    }
    float s0 = v.x * v.x, s1 = v.y * v.y, s2 = v.z * v.z, s3 = v.w * v.w;
    double qd = (double)s0 + (double)s1 + (double)s2 + (double)s3;
    #pragma unroll
    for (int off = 32; off; off >>= 1) qd += __shfl_xor(qd, off, 64);
    if (lane == 0) {
        float cf = (float)qd;
        C[row] = cf;
        if (etiles)
            *(float*)(etiles + (size_t)tile * TILE_B + 8192 + jj * 4) = cf;
    }
}

// ---------------------------------------------------------------------------
// Exact fp32 score, bit-identical arithmetic to the proven-passing kernel.
__device__ __forceinline__ unsigned long long exact_pack(
    const float* __restrict__ emb, const float* __restrict__ C,
    const float* __restrict__ xsrow, float rowA, int k)
{
    const float4* er = (const float4*)(emb + (size_t)k * DIM);
    float acc = 0.f;
    #pragma unroll 8
    for (int d4 = 0; d4 < DIM / 4; ++d4) {
        float4 ev = er[d4];
        float4 xv = *(const float4*)(xsrow + d4 * 4);
        acc = fmaf(xv.x, ev.x, acc);
        acc = fmaf(xv.y, ev.y, acc);
        acc = fmaf(xv.z, ev.z, acc);
        acc = fmaf(xv.w, ev.w, acc);
    }
    float tmp = rowA - 2.0f * acc;
    float sc  = tmp + C[k];
    // exact scores are squared distances (positive): bit pattern is monotone
    return ((unsigned long long)__float_as_uint(sc) << 32) | (unsigned)k;
}

// Two candidates interleaved (independent fmaf chains -> 2x ILP).
__device__ __forceinline__ unsigned long long exact_pack2(
    const float* __restrict__ emb, const float* __restrict__ C,
    const float* __restrict__ xsrow, float rowA, int k1, int k2)
{
    const float4* e1 = (const float4*)(emb + (size_t)k1 * DIM);
    const float4* e2 = (const float4*)(emb + (size_t)k2 * DIM);
    float a1 = 0.f, a2 = 0.f;
    #pragma unroll 8
    for (int d4 = 0; d4 < DIM / 4; ++d4) {
        float4 xv = *(const float4*)(xsrow + d4 * 4);
        float4 v1 = e1[d4];
        float4 v2 = e2[d4];
        a1 = fmaf(xv.x, v1.x, a1);  a2 = fmaf(xv.x, v2.x, a2);
        a1 = fmaf(xv.y, v1.y, a1);  a2 = fmaf(xv.y, v2.y, a2);
        a1 = fmaf(xv.z, v1.z, a1);  a2 = fmaf(xv.z, v2.z, a2);
        a1 = fmaf(xv.w, v1.w, a1);  a2 = fmaf(xv.w, v2.w, a2);
    }
    float s1 = (rowA - 2.0f * a1) + C[k1];
    float s2 = (rowA - 2.0f * a2) + C[k2];
    unsigned long long p1 = ((unsigned long long)__float_as_uint(s1) << 32) | (unsigned)k1;
    unsigned long long p2 = ((unsigned long long)__float_as_uint(s2) << 32) | (unsigned)k2;
    return p1 < p2 ? p1 : p2;
}

// ---------------------------------------------------------------------------
// Kernel C: SINGLE bf16-MFMA sweep with MONOTONE shared threshold.
// thrRow[] holds positive-float bit patterns updated ONLY via atomicMin(u32)
// (float order == bit order for positive floats), so the threshold can never
// rise. Every stored value is (some seen score)+MARGIN >= approx(true argmin),
// so staleness/concurrency only over-collect -- correctness is unconditional,
// with the CAP-overflow -> full exact rescan fallback as the last resort.
__global__ __launch_bounds__(256, 2) void vq_mfma(
    const float* __restrict__ x, const float* __restrict__ emb,
    const unsigned char* __restrict__ etiles,
    const float* __restrict__ A, const float* __restrict__ C,
    float* __restrict__ out, double* __restrict__ lossAcc)
{
    __shared__ union {
        float xstage[MROWS][XSP];                 // 66560 B (prologue only)
        unsigned char ebuf[4][2][TILE_B];         // 67584 B (sweep: per-wave dbuf)
    } sh;
    __shared__ int    cand[MROWS][CAP];           // 8192
    __shared__ int    cnt[MROWS];
    __shared__ float  thrRow[MROWS];              // monotone threshold (atomicMin bits)
    __shared__ int    sIdx[MROWS];
    __shared__ double sRed[4];
    __shared__ unsigned long long bestA[4][MROWS];

    const int tid = threadIdx.x;
    const int w   = tid >> 6;        // wave 0..3 (owns code-tiles j*4+w)
    const int l   = tid & 63;
    const int jj  = l & 15;          // MFMA col lane (code within tile)
    const int g   = l >> 4;          // MFMA k-group / D row group
    const int rowBase = blockIdx.x * MROWS;

    // ---- stage x tile into (padded) LDS for the frag build ----
    #pragma unroll
    for (int p = 0; p < 16; ++p) {
        int flat = p * 256 + tid;
        int row = flat >> 6, d = (flat & 63) * 4;
        *(float4*)&sh.xstage[row][d] = *(const float4*)(x + (size_t)(rowBase + row) * DIM + d);
    }
    if (tid < MROWS) { cnt[tid] = 0; thrRow[tid] = 3.4e38f; }
    __syncthreads();

    // ---- build all A fragments: 4 row-tiles x 8 k-steps (128 regs) ----
    short8v Af[4][8];
    #pragma unroll
    for (int t = 0; t < 4; ++t)
        #pragma unroll
        for (int s = 0; s < 8; ++s) {
            const float* xp = &sh.xstage[t * 16 + jj][s * 32 + g * 8];
            float4 a = *(const float4*)xp;
            float4 b = *(const float4*)(xp + 4);
            short8v f;
            f[0] = (short)f2bf_rne(a.x); f[1] = (short)f2bf_rne(a.y);
            f[2] = (short)f2bf_rne(a.z); f[3] = (short)f2bf_rne(a.w);
            f[4] = (short)f2bf_rne(b.x); f[5] = (short)f2bf_rne(b.y);
            f[6] = (short)f2bf_rne(b.z); f[7] = (short)f2bf_rne(b.w);
            Af[t][s] = f;
        }
    __syncthreads();   // all waves done reading xstage before ebuf overwrite

    // swizzled per-lane B-frag byte offsets (constant over tiles)
    const int fsw = ((jj >> 1) & 3) | ((jj & 1) << 2);
    int boff[8];
    #pragma unroll
    for (int s = 0; s < 8; ++s)
        boff[s] = ((jj * 32 + s * 4 + g) ^ fsw) * 16;

    unsigned char* b0 = sh.ebuf[w][0];
    unsigned char* b1 = sh.ebuf[w][1];

    // STAGE: 9 async global->LDS ops for tile NT into BUF (wave-private)
#define STAGE(BUF, NT)                                                        \
    {                                                                         \
        const unsigned char* src_ = etiles + (size_t)(NT) * TILE_B;           \
        _Pragma("unroll")                                                     \
        for (int j_ = 0; j_ < 8; ++j_)                                        \
            gld16(src_ + j_ * 1024 + l * 16, (BUF) + j_ * 1024);              \
        gld4(src_ + 8192 + l * 4, (BUF) + 8192);                              \
    }

    // MFMADOT: waits (counted), 32 MFMA on BUF -> acc0..acc3, loads Cv
#define MFMADOT(BUF, WAITN)                                                   \
        asm volatile("s_waitcnt vmcnt(" WAITN ")" ::: "memory");              \
        float Cv = *(const float*)((BUF) + 8192 + jj * 4);                    \
        f32x4 acc0 = {0,0,0,0}, acc1 = {0,0,0,0};                             \
        f32x4 acc2 = {0,0,0,0}, acc3 = {0,0,0,0};                             \
        __builtin_amdgcn_s_setprio(1);                                        \
        _Pragma("unroll")                                                     \
        for (int s_ = 0; s_ < 8; ++s_) {                                      \
            short8v B_ = *(const short8v*)((BUF) + boff[s_]);                 \
            acc0 = __builtin_amdgcn_mfma_f32_16x16x32_bf16(Af[0][s_], B_, acc0, 0, 0, 0); \
            acc1 = __builtin_amdgcn_mfma_f32_16x16x32_bf16(Af[1][s_], B_, acc1, 0, 0, 0); \
            acc2 = __builtin_amdgcn_mfma_f32_16x16x32_bf16(Af[2][s_], B_, acc2, 0, 0, 0); \
            acc3 = __builtin_amdgcn_mfma_f32_16x16x32_bf16(Af[3][s_], B_, acc3, 0, 0, 0); \
        }                                                                     \
        __builtin_amdgcn_s_setprio(0);

    // COLLECT1: threshold test + candidate append + monotone thr tighten.
    // Guard vs stale thrv is conservative-correct: actual thr <= stale thr.
#define COLLECT1(SC, T, R)                                                    \
            if ((SC) <= thrv[T][R]) {                                         \
                int row_ = (T) * 16 + g * 4 + (R);                            \
                int p_ = atomicAdd(&cnt[row_], 1);                            \
                if (p_ < CAP) cand[row_][p_] = kc_;                           \
                if ((SC) + MARGIN < thrv[T][R])                               \
                    atomicMin((unsigned int*)&thrRow[row_],                   \
                              __float_as_uint((SC) + MARGIN));                \
            }

    // COMPUTE: MFMADOT + fresh thr load (post-MFMA) + collection for tile NT
#define COMPUTE(BUF, NT, WAITN)                                               \
    {                                                                         \
        MFMADOT(BUF, WAITN)                                                   \
        float4 thrv[4];                                                       \
        _Pragma("unroll")                                                     \
        for (int t_ = 0; t_ < 4; ++t_)                                        \
            thrv[t_] = *(const float4*)&thrRow[t_ * 16 + g * 4];              \
        int kc_ = (NT) * 16 + jj;                                             \
        _Pragma("unroll")                                                     \
        for (int r_ = 0; r_ < 4; ++r_) {                                      \
            float s0_ = fmaf(-2.f, acc0[r_], Cv);                             \
            float s1_ = fmaf(-2.f, acc1[r_], Cv);                             \
            float s2_ = fmaf(-2.f, acc2[r_], Cv);                             \
            float s3_ = fmaf(-2.f, acc3[r_], Cv);                             \
            COLLECT1(s0_, 0, r_)                                              \
            COLLECT1(s1_, 1, r_)                                              \
            COLLECT1(s2_, 2, r_)                                              \
            COLLECT1(s3_, 3, r_)                                              \
        }                                                                     \
    }

    // ---- iter 0: seed thrRow via atomicMin (true min over 64 codes) ----
    STAGE(b0, w);
    STAGE(b1, 4 + w);
    float sc0[16];
    {
        MFMADOT(b0, "9")
        #pragma unroll
        for (int r_ = 0; r_ < 4; ++r_) {
            sc0[0 * 4 + r_] = fmaf(-2.f, acc0[r_], Cv);
            sc0[1 * 4 + r_] = fmaf(-2.f, acc1[r_], Cv);
            sc0[2 * 4 + r_] = fmaf(-2.f, acc2[r_], Cv);
            sc0[3 * 4 + r_] = fmaf(-2.f, acc3[r_], Cv);
        }
        // reduce each (t,r) min across the 16 code-lanes; jj==0 seeds via atomicMin
        #pragma unroll
        for (int t = 0; t < 4; ++t)
            #pragma unroll
            for (int r = 0; r < 4; ++r) {
                float v = sc0[t * 4 + r];
                #pragma unroll
                for (int off = 1; off <= 8; off <<= 1)
                    v = fminf(v, __shfl_xor(v, off, 16));
                if (jj == 0)
                    atomicMin((unsigned int*)&thrRow[t * 16 + g * 4 + r],
                              __float_as_uint(v + MARGIN));
            }
    }
    __syncthreads();   // thr = min-of-64 + MARGIN (also drains b1's stage)

    // collect iter-0 scores against the seeded thresholds
    {
        int kc0 = w * 16 + jj;
        #pragma unroll
        for (int t = 0; t < 4; ++t)
            #pragma unroll
            for (int r = 0; r < 4; ++r) {
                float sc = sc0[t * 4 + r];
                int row_ = t * 16 + g * 4 + r;
                if (sc <= thrRow[row_]) {
                    int p_ = atomicAdd(&cnt[row_], 1);
                    if (p_ < CAP) cand[row_][p_] = kc0;
                }
            }
    }

    // ---- main sweep: tiles j=1..63 (wave-private pipeline, no barriers) ----
    #pragma unroll 1
    for (int j = 1; j < 62; j += 2) {
        STAGE(b0, (j + 1) * 4 + w);
        COMPUTE(b1, j * 4 + w, "9");
        STAGE(b1, (j + 2) * 4 + w);
        COMPUTE(b0, (j + 1) * 4 + w, "9");
    }
    COMPUTE(b1, 63 * 4 + w, "0");       // final tile: drain
    __syncthreads();                    // cand/cnt visible to all

#undef STAGE
#undef MFMADOT
#undef COLLECT1
#undef COMPUTE

    // ---- exact fp32 rescore of candidates (4 threads per row, 2-way ILP) ----
    const int crow = tid & 63;
    const int sub  = tid >> 6;
    unsigned long long best = ~0ULL;
    {
        int cc = cnt[crow];
        float rowA = A[rowBase + crow];
        const float* xsrow = x + (size_t)(rowBase + crow) * DIM;
        if (cc <= CAP) {
            int c = sub;
            for (; c + 4 < cc; c += 8) {
                unsigned long long pk = exact_pack2(emb, C, xsrow, rowA,
                                                   cand[crow][c], cand[crow][c + 4]);
                best = best < pk ? best : pk;
            }
            if (c < cc) {
                unsigned long long pk = exact_pack(emb, C, xsrow, rowA, cand[crow][c]);
                best = best < pk ? best : pk;
            }
        } else {
            // overflow fallback (prob ~0 with monotone thr): full exact row scan
            for (int k = sub; k < KCB; k += 8) {
                unsigned long long pk = exact_pack2(emb, C, xsrow, rowA, k, k + 4);
                best = best < pk ? best : pk;
            }
        }
    }
    bestA[sub][crow] = best;
    __syncthreads();
    if (tid < MROWS) {
        unsigned long long v0 = bestA[0][tid], v1 = bestA[1][tid];
        unsigned long long v2 = bestA[2][tid], v3 = bestA[3][tid];
        unsigned long long b = v0 < v1 ? v0 : v1;
        unsigned long long c2 = v2 < v3 ? v2 : v3;
        b = b < c2 ? b : c2;
        int idx = (int)(unsigned)(b & 0xFFFFFFFFull);
        sIdx[tid] = idx;
        out[1 + (size_t)N_TOK * DIM + rowBase + tid] = (float)idx;
    }
    __syncthreads();

    // ---- outputs: quantized gather (exact) + fp64 loss partial ----
    double lsum = 0.0;
    for (int row = 0; row < MROWS; ++row) {
        int idx = sIdx[row];
        float q  = emb[(size_t)idx * DIM + tid];
        float xv = x[(size_t)(rowBase + row) * DIM + tid];
        out[1 + (size_t)(rowBase + row) * DIM + tid] = q;
        double df = (double)q - (double)xv;
        lsum += df * df;
    }
    #pragma unroll
    for (int off = 1; off < 64; off <<= 1) lsum += __shfl_xor(lsum, off, 64);
    __syncthreads();
    if ((tid & 63) == 0) sRed[tid >> 6] = lsum;
    __syncthreads();
    if (tid == 0) atomicAdd(lossAcc, sRed[0] + sRed[1] + sRed[2] + sRed[3]);
}

// ---------------------------------------------------------------------------
// Legacy kernel (proven-passing), fallback if ws is too small.
__global__ __launch_bounds__(256, 2) void vq_np(
    const float* __restrict__ x, const float* __restrict__ emb,
    const float* __restrict__ A, const float* __restrict__ C,
    float* __restrict__ out, double* __restrict__ lossAcc)
{
    __shared__ float xs[MROWS][DIM];
    __shared__ float est[DC][ESD];
    __shared__ float sA[MROWS];
    __shared__ int   sIdx[MROWS];
    __shared__ double sRed[4];

    const int tid = threadIdx.x;
    const int c = tid & 31;
    const int r = tid >> 5;
    const int rowBase = blockIdx.x * MROWS;

    if (tid < MROWS) sA[tid] = A[rowBase + tid];

    #pragma unroll
    for (int p = 0; p < 16; ++p) {
        int flat = p * 256 + tid;
        int row = flat >> 6, d = (flat & 63) * 4;
        float4 v = *(const float4*)(x + (size_t)(rowBase + row) * DIM + d);
        *(float4*)&xs[row][d] = v;
    }

    float m1[8];
    int   i1[8];
    #pragma unroll
    for (int ri = 0; ri < 8; ++ri) { m1[ri] = 3.4e38f; i1[ri] = 0; }

    for (int kt = 0; kt < NKT; ++kt) {
        float acc[8][8];
        #pragma unroll
        for (int ri = 0; ri < 8; ++ri)
            #pragma unroll
            for (int kk = 0; kk < 8; ++kk) acc[ri][kk] = 0.f;

        for (int dc = 0; dc < NDC; ++dc) {
            const float* src = emb + (size_t)(kt * KT + tid) * DIM + dc * DC;
            float4 ea = *(const float4*)(src);
            float4 eb = *(const float4*)(src + 4);
            __syncthreads();
            est[0][tid] = ea.x; est[1][tid] = ea.y; est[2][tid] = ea.z; est[3][tid] = ea.w;
            est[4][tid] = eb.x; est[5][tid] = eb.y; est[6][tid] = eb.z; est[7][tid] = eb.w;
            __syncthreads();
            #pragma unroll
            for (int d4 = 0; d4 < 2; ++d4) {
                float4 xf[8];
                #pragma unroll
                for (int ri = 0; ri < 8; ++ri)
                    xf[ri] = *(const float4*)&xs[r * 8 + ri][dc * DC + d4 * 4];
                #pragma unroll
                for (int dd = 0; dd < 4; ++dd) {
                    float2 ev[4];
                    #pragma unroll
                    for (int j = 0; j < 4; ++j)
                        ev[j] = *(const float2*)&est[d4 * 4 + dd][2 * c + 64 * j];
                    #pragma unroll
                    for (int ri = 0; ri < 8; ++ri) {
                        float xv = (dd == 0) ? xf[ri].x : (dd == 1) ? xf[ri].y
                                 : (dd == 2) ? xf[ri].z : xf[ri].w;
                        #pragma unroll
                        for (int j = 0; j < 4; ++j) {
                            acc[ri][2 * j]     = fmaf(xv, ev[j].x, acc[ri][2 * j]);
                            acc[ri][2 * j + 1] = fmaf(xv, ev[j].y, acc[ri][2 * j + 1]);
                        }
                    }
                }
            }
        }
        #pragma unroll
        for (int j = 0; j < 4; ++j) {
            float2 Cv = *(const float2*)&C[kt * KT + 2 * c + 64 * j];
            #pragma unroll
            for (int p = 0; p < 2; ++p) {
                int kg = kt * KT + 2 * c + 64 * j + p;
                float Ck = (p == 0) ? Cv.x : Cv.y;
                #pragma unroll
                for (int ri = 0; ri < 8; ++ri) {
                    float tmp = sA[r * 8 + ri] - 2.0f * acc[ri][2 * j + p];
                    float s   = tmp + Ck;
                    if (s < m1[ri]) { m1[ri] = s; i1[ri] = kg; }
                }
            }
        }
    }

    #pragma unroll
    for (int ri = 0; ri < 8; ++ri) {
        float a = m1[ri]; int ja = i1[ri];
        #pragma unroll
        for (int off = 1; off <= 16; off <<= 1) {
            float b  = __shfl_xor(a, off, 64);
            int   jb = __shfl_xor(ja, off, 64);
            if (b < a || (b == a && jb < ja)) { a = b; ja = jb; }
        }
        if (c == 0) sIdx[r * 8 + ri] = ja;
    }
    __syncthreads();

    if (tid < MROWS) {
        out[1 + (size_t)N_TOK * DIM + rowBase + tid] = (float)sIdx[tid];
    }
    double lsum = 0.0;
    for (int row = 0; row < MROWS; ++row) {
        int idx = sIdx[row];
        float q  = emb[(size_t)idx * DIM + tid];
        float xv = xs[row][tid];
        out[1 + (size_t)(rowBase + row) * DIM + tid] = q;
        double df = (double)q - (double)xv;
        lsum += df * df;
    }
    #pragma unroll
    for (int off = 1; off < 64; off <<= 1) lsum += __shfl_xor(lsum, off, 64);
    __syncthreads();
    if ((tid & 63) == 0) sRed[tid >> 6] = lsum;
    __syncthreads();
    if (tid == 0) {
        atomicAdd(lossAcc, sRed[0] + sRed[1] + sRed[2] + sRed[3]);
    }
}

// ---------------------------------------------------------------------------
__global__ void finalize_kernel(const double* __restrict__ lossAcc, float* __restrict__ out) {
    out[0] = (float)(0.5 * (*lossAcc) / (double)((size_t)N_TOK * DIM));
}

extern "C" void kernel_launch(void* const* d_in, const int* in_sizes, int n_in,
                              void* d_out, int out_size, void* d_ws, size_t ws_size,
                              hipStream_t stream) {
    const float* x   = (const float*)d_in[0];   // [16,2048,256] fp32
    const float* emb = (const float*)d_in[1];   // [4096,256] fp32
    float* out = (float*)d_out;

    double* lossAcc = (double*)d_ws;
    float*  A       = (float*)((char*)d_ws + WS_A);
    float*  C       = (float*)((char*)d_ws + WS_C);
    unsigned char* etiles = (unsigned char*)((char*)d_ws + WS_E);

    const bool use_new = ws_size >= WS_NEED_NEW;

    hipMemsetAsync(d_ws, 0, 16, stream);
    xsq_np_kernel<<<N_TOK / 4, 256, 0, stream>>>(x, A);
    esq_np_kernel<<<KCB / 4, 256, 0, stream>>>(emb, C, use_new ? etiles : nullptr);
    if (use_new)
        vq_mfma<<<N_TOK / MROWS, 256, 0, stream>>>(x, emb, etiles, A, C, out, lossAcc);
    else
        vq_np<<<N_TOK / MROWS, 256, 0, stream>>>(x, emb, A, C, out, lossAcc);
    finalize_kernel<<<1, 1, 0, stream>>>(lossAcc, out);
}

// Round 8
// 3574.400 us; speedup vs baseline: 3.0863x; 3.0863x over previous
//
#include <hip/hip_runtime.h>

#define N_TOK 32768
#define DIM   256
#define KCB   4096
#define MROWS 64           // rows per block
#define XSP   260          // padded xstage row stride (floats)
#define NTILE (KCB / 16)   // 256 code-tiles of 16 codes
#define TILE_B 8448        // 16*256*2 (bf16, swizzled) + 256 (C floats, 64B valid)
// ---- legacy-kernel tile params (fallback path) ----
#define KT    256
#define NKT   (KCB / KT)
#define DC    8
#define NDC   (DIM / DC)
#define ESD   258

// ws layout (bytes):
//   0      : double lossAcc (zeroed by 16B memset)
//   16     : float A[N_TOK]  -- numpy-replica fp32 ||x_i||^2
//   131088 : float C[KCB]    -- fp32 ||e_k||^2
//   147472 : etiles[256][8448] -- pre-swizzled bf16 code-tiles + appended C
#define WS_A 16
#define WS_C (16 + 4 * N_TOK)
#define WS_E (WS_C + 4 * KCB)
#define WS_NEED_NEW ((size_t)WS_E + (size_t)NTILE * TILE_B)

#define CAP    48          // candidate list capacity per row
#define MARGIN 1.5e-3f     // >= 2x worst-case bf16-approx score error (~5e-4 hard)
// Approx scores are biased by +1.0f: sb = 1 + C - 2*dot in [~0.98, ~1.02].
// POSITIVE by construction -> u32 bit pattern is float-order-monotone, so
// atomicMin-on-bits == float-min. (Round-5 bug: unbiased scores were negative,
// every atomicMin was a no-op, thr stayed +inf, all rows overflowed to the
// exact-scan fallback.) Bias quantization error <= 2.4e-7 << MARGIN.

typedef __attribute__((ext_vector_type(8))) short short8v;  // 8 x bf16 bits
typedef __attribute__((ext_vector_type(4))) float f32x4;

__device__ __forceinline__ unsigned short f2bf_rne(float f) {
    unsigned u = __float_as_uint(f);
    unsigned r = (u + 0x7FFFu + ((u >> 16) & 1u)) >> 16;
    return (unsigned short)r;
}

// async global->LDS staging helpers (size must be literal)
__device__ __forceinline__ void gld16(const void* g, void* l) {
    __builtin_amdgcn_global_load_lds(
        (const __attribute__((address_space(1))) unsigned int*)g,
        (__attribute__((address_space(3))) unsigned int*)l, 16, 0, 0);
}
__device__ __forceinline__ void gld4(const void* g, void* l) {
    __builtin_amdgcn_global_load_lds(
        (const __attribute__((address_space(1))) unsigned int*)g,
        (__attribute__((address_space(3))) unsigned int*)l, 4, 0, 0);
}

// ---------------------------------------------------------------------------
// Kernel A: bit-exact replica of numpy's fp32 pairwise row sum-of-squares.
__global__ __launch_bounds__(256) void xsq_np_kernel(const float* __restrict__ x,
                                                     float* __restrict__ A) {
#pragma clang fp contract(off)
    __shared__ float xr[4][256];
    const int tid = threadIdx.x;
    const int w = tid >> 6, l = tid & 63;
    const int row = blockIdx.x * 4 + w;
    float4 v = *(const float4*)(x + (size_t)row * DIM + l * 4);
    xr[w][l * 4 + 0] = v.x; xr[w][l * 4 + 1] = v.y;
    xr[w][l * 4 + 2] = v.z; xr[w][l * 4 + 3] = v.w;
    __syncthreads();
    const float* t = xr[w];
    const int g = (l >> 4) & 1;
    const int j = l & 15;
    const int base = g * 128 + j;
    float t0 = t[base +   0] * t[base +   0];
    float t1 = t[base +  16] * t[base +  16];
    float t2 = t[base +  32] * t[base +  32];
    float t3 = t[base +  48] * t[base +  48];
    float t4 = t[base +  64] * t[base +  64];
    float t5 = t[base +  80] * t[base +  80];
    float t6 = t[base +  96] * t[base +  96];
    float t7 = t[base + 112] * t[base + 112];
    float p = ((t0 + t1) + (t2 + t3)) + ((t4 + t5) + (t6 + t7));
    p = p + __shfl_xor(p, 8, 64);
    p = p + __shfl_xor(p, 4, 64);
    p = p + __shfl_xor(p, 2, 64);
    p = p + __shfl_xor(p, 1, 64);
    float other = __shfl(p, 16, 64);
    if (l == 0) A[row] = p + other;
}

// ---------------------------------------------------------------------------
// Kernel B: C[k] exact; also emits PRE-SWIZZLED bf16 tiles + appended C.
// Rotation swizzle: 16B unit u stored at u ^ f(jj), f(jj)=((jj>>1)&3)|((jj&1)<<2).
__global__ void esq_np_kernel(const float* __restrict__ emb, float* __restrict__ C,
                              unsigned char* __restrict__ etiles) {
#pragma clang fp contract(off)
    int row  = blockIdx.x * 4 + (threadIdx.x >> 6);
    int lane = threadIdx.x & 63;
    float4 v = *(const float4*)(emb + (size_t)row * DIM + lane * 4);
    int tile = row >> 4, jj = row & 15;
    if (etiles) {
        ushort4 h;
        h.x = f2bf_rne(v.x); h.y = f2bf_rne(v.y);
        h.z = f2bf_rne(v.z); h.w = f2bf_rne(v.w);
        int f  = ((jj >> 1) & 3) | ((jj & 1) << 2);
        int u  = jj * 32 + (lane >> 1);      // 16B unit within tile
        int qs = u ^ f;                      // swizzled unit (stays in row: f<8<32)
        *(ushort4*)(etiles + (size_t)tile * TILE_B + qs * 16 + (lane & 1) * 8) = h;
    }
    float s0 = v.x * v.x, s1 = v.y * v.y, s2 = v.z * v.z, s3 = v.w * v.w;
    double qd = (double)s0 + (double)s1 + (double)s2 + (double)s3;
    #pragma unroll
    for (int off = 32; off; off >>= 1) qd += __shfl_xor(qd, off, 64);
    if (lane == 0) {
        float cf = (float)qd;
        C[row] = cf;
        if (etiles)
            *(float*)(etiles + (size_t)tile * TILE_B + 8192 + jj * 4) = cf;
    }
}

// ---------------------------------------------------------------------------
// Exact fp32 score, bit-identical arithmetic to the proven-passing kernel.
__device__ __forceinline__ unsigned long long exact_pack(
    const float* __restrict__ emb, const float* __restrict__ C,
    const float* __restrict__ xsrow, float rowA, int k)
{
    const float4* er = (const float4*)(emb + (size_t)k * DIM);
    float acc = 0.f;
    #pragma unroll 8
    for (int d4 = 0; d4 < DIM / 4; ++d4) {
        float4 ev = er[d4];
        float4 xv = *(const float4*)(xsrow + d4 * 4);
        acc = fmaf(xv.x, ev.x, acc);
        acc = fmaf(xv.y, ev.y, acc);
        acc = fmaf(xv.z, ev.z, acc);
        acc = fmaf(xv.w, ev.w, acc);
    }
    float tmp = rowA - 2.0f * acc;
    float sc  = tmp + C[k];
    // exact scores are squared distances (positive): bit pattern is monotone
    return ((unsigned long long)__float_as_uint(sc) << 32) | (unsigned)k;
}

// Two candidates interleaved (independent fmaf chains -> 2x ILP).
__device__ __forceinline__ unsigned long long exact_pack2(
    const float* __restrict__ emb, const float* __restrict__ C,
    const float* __restrict__ xsrow, float rowA, int k1, int k2)
{
    const float4* e1 = (const float4*)(emb + (size_t)k1 * DIM);
    const float4* e2 = (const float4*)(emb + (size_t)k2 * DIM);
    float a1 = 0.f, a2 = 0.f;
    #pragma unroll 8
    for (int d4 = 0; d4 < DIM / 4; ++d4) {
        float4 xv = *(const float4*)(xsrow + d4 * 4);
        float4 v1 = e1[d4];
        float4 v2 = e2[d4];
        a1 = fmaf(xv.x, v1.x, a1);  a2 = fmaf(xv.x, v2.x, a2);
        a1 = fmaf(xv.y, v1.y, a1);  a2 = fmaf(xv.y, v2.y, a2);
        a1 = fmaf(xv.z, v1.z, a1);  a2 = fmaf(xv.z, v2.z, a2);
        a1 = fmaf(xv.w, v1.w, a1);  a2 = fmaf(xv.w, v2.w, a2);
    }
    float s1 = (rowA - 2.0f * a1) + C[k1];
    float s2 = (rowA - 2.0f * a2) + C[k2];
    unsigned long long p1 = ((unsigned long long)__float_as_uint(s1) << 32) | (unsigned)k1;
    unsigned long long p2 = ((unsigned long long)__float_as_uint(s2) << 32) | (unsigned)k2;
    return p1 < p2 ? p1 : p2;
}

// ---------------------------------------------------------------------------
// Kernel C: SINGLE bf16-MFMA sweep with MONOTONE shared threshold on BIASED
// (positive) approx scores. thrRow[] updated only via atomicMin on u32 bits
// (valid: scores > 0), so thr never rises; every stored value is
// (seen biased score)+MARGIN >= biased-approx(true argmin), so staleness only
// over-collects. CAP-overflow -> full exact row scan remains the safety net.
__global__ __launch_bounds__(256, 2) void vq_mfma(
    const float* __restrict__ x, const float* __restrict__ emb,
    const unsigned char* __restrict__ etiles,
    const float* __restrict__ A, const float* __restrict__ C,
    float* __restrict__ out, double* __restrict__ lossAcc)
{
    __shared__ union {
        float xstage[MROWS][XSP];                 // 66560 B (prologue only)
        unsigned char ebuf[4][2][TILE_B];         // 67584 B (sweep: per-wave dbuf)
        unsigned long long bestA[4][MROWS];       // 2048 B (post-sweep only)
    } sh;
    __shared__ int    cand[MROWS][CAP];           // 12288
    __shared__ int    cnt[MROWS];
    __shared__ float  thrRow[MROWS];              // monotone threshold (atomicMin bits)
    __shared__ int    sIdx[MROWS];
    __shared__ double sRed[4];

    const int tid = threadIdx.x;
    const int w   = tid >> 6;        // wave 0..3 (owns code-tiles j*4+w)
    const int l   = tid & 63;
    const int jj  = l & 15;          // MFMA col lane (code within tile)
    const int g   = l >> 4;          // MFMA k-group / D row group
    const int rowBase = blockIdx.x * MROWS;

    // ---- stage x tile into (padded) LDS for the frag build ----
    #pragma unroll
    for (int p = 0; p < 16; ++p) {
        int flat = p * 256 + tid;
        int row = flat >> 6, d = (flat & 63) * 4;
        *(float4*)&sh.xstage[row][d] = *(const float4*)(x + (size_t)(rowBase + row) * DIM + d);
    }
    if (tid < MROWS) { cnt[tid] = 0; thrRow[tid] = 3.4e38f; }
    __syncthreads();

    // ---- build all A fragments: 4 row-tiles x 8 k-steps (128 regs) ----
    short8v Af[4][8];
    #pragma unroll
    for (int t = 0; t < 4; ++t)
        #pragma unroll
        for (int s = 0; s < 8; ++s) {
            const float* xp = &sh.xstage[t * 16 + jj][s * 32 + g * 8];
            float4 a = *(const float4*)xp;
            float4 b = *(const float4*)(xp + 4);
            short8v f;
            f[0] = (short)f2bf_rne(a.x); f[1] = (short)f2bf_rne(a.y);
            f[2] = (short)f2bf_rne(a.z); f[3] = (short)f2bf_rne(a.w);
            f[4] = (short)f2bf_rne(b.x); f[5] = (short)f2bf_rne(b.y);
            f[6] = (short)f2bf_rne(b.z); f[7] = (short)f2bf_rne(b.w);
            Af[t][s] = f;
        }
    __syncthreads();   // all waves done reading xstage before ebuf overwrite

    // swizzled per-lane B-frag byte offsets (constant over tiles)
    const int fsw = ((jj >> 1) & 3) | ((jj & 1) << 2);
    int boff[8];
    #pragma unroll
    for (int s = 0; s < 8; ++s)
        boff[s] = ((jj * 32 + s * 4 + g) ^ fsw) * 16;

    unsigned char* b0 = sh.ebuf[w][0];
    unsigned char* b1 = sh.ebuf[w][1];

    // STAGE: 9 async global->LDS ops for tile NT into BUF (wave-private)
#define STAGE(BUF, NT)                                                        \
    {                                                                         \
        const unsigned char* src_ = etiles + (size_t)(NT) * TILE_B;           \
        _Pragma("unroll")                                                     \
        for (int j_ = 0; j_ < 8; ++j_)                                        \
            gld16(src_ + j_ * 1024 + l * 16, (BUF) + j_ * 1024);              \
        gld4(src_ + 8192 + l * 4, (BUF) + 8192);                              \
    }

    // MFMADOT: waits (counted), 32 MFMA on BUF -> acc0..acc3; CvB = 1 + C
#define MFMADOT(BUF, WAITN)                                                   \
        asm volatile("s_waitcnt vmcnt(" WAITN ")" ::: "memory");              \
        float CvB = 1.0f + *(const float*)((BUF) + 8192 + jj * 4);            \
        f32x4 acc0 = {0,0,0,0}, acc1 = {0,0,0,0};                             \
        f32x4 acc2 = {0,0,0,0}, acc3 = {0,0,0,0};                             \
        __builtin_amdgcn_s_setprio(1);                                        \
        _Pragma("unroll")                                                     \
        for (int s_ = 0; s_ < 8; ++s_) {                                      \
            short8v B_ = *(const short8v*)((BUF) + boff[s_]);                 \
            acc0 = __builtin_amdgcn_mfma_f32_16x16x32_bf16(Af[0][s_], B_, acc0, 0, 0, 0); \
            acc1 = __builtin_amdgcn_mfma_f32_16x16x32_bf16(Af[1][s_], B_, acc1, 0, 0, 0); \
            acc2 = __builtin_amdgcn_mfma_f32_16x16x32_bf16(Af[2][s_], B_, acc2, 0, 0, 0); \
            acc3 = __builtin_amdgcn_mfma_f32_16x16x32_bf16(Af[3][s_], B_, acc3, 0, 0, 0); \
        }                                                                     \
        __builtin_amdgcn_s_setprio(0);

    // COLLECT1: threshold test + candidate append + monotone thr tighten.
    // Stale thrv only over-collects (actual thr <= stale thr). SC positive.
#define COLLECT1(SC, T, R)                                                    \
            if ((SC) <= thrv[T][R]) {                                         \
                int row_ = (T) * 16 + g * 4 + (R);                            \
                int p_ = atomicAdd(&cnt[row_], 1);                            \
                if (p_ < CAP) cand[row_][p_] = kc_;                           \
                if ((SC) + MARGIN < thrv[T][R])                               \
                    atomicMin((unsigned int*)&thrRow[row_],                   \
                              __float_as_uint((SC) + MARGIN));                \
            }

    // COMPUTE: MFMADOT + fresh thr load (post-MFMA) + collection for tile NT
#define COMPUTE(BUF, NT, WAITN)                                               \
    {                                                                         \
        MFMADOT(BUF, WAITN)                                                   \
        float4 thrv[4];                                                       \
        _Pragma("unroll")                                                     \
        for (int t_ = 0; t_ < 4; ++t_)                                        \
            thrv[t_] = *(const float4*)&thrRow[t_ * 16 + g * 4];              \
        int kc_ = (NT) * 16 + jj;                                             \
        _Pragma("unroll")                                                     \
        for (int r_ = 0; r_ < 4; ++r_) {                                      \
            float s0_ = fmaf(-2.f, acc0[r_], CvB);                            \
            float s1_ = fmaf(-2.f, acc1[r_], CvB);                            \
            float s2_ = fmaf(-2.f, acc2[r_], CvB);                            \
            float s3_ = fmaf(-2.f, acc3[r_], CvB);                            \
            COLLECT1(s0_, 0, r_)                                              \
            COLLECT1(s1_, 1, r_)                                              \
            COLLECT1(s2_, 2, r_)                                              \
            COLLECT1(s3_, 3, r_)                                              \
        }                                                                     \
    }

    // ---- iter 0: seed thrRow via atomicMin (true min over 64 codes) ----
    STAGE(b0, w);
    STAGE(b1, 4 + w);
    float sc0[16];
    {
        MFMADOT(b0, "9")
        #pragma unroll
        for (int r_ = 0; r_ < 4; ++r_) {
            sc0[0 * 4 + r_] = fmaf(-2.f, acc0[r_], CvB);
            sc0[1 * 4 + r_] = fmaf(-2.f, acc1[r_], CvB);
            sc0[2 * 4 + r_] = fmaf(-2.f, acc2[r_], CvB);
            sc0[3 * 4 + r_] = fmaf(-2.f, acc3[r_], CvB);
        }
        // reduce each (t,r) min across the 16 code-lanes; jj==0 seeds via atomicMin
        #pragma unroll
        for (int t = 0; t < 4; ++t)
            #pragma unroll
            for (int r = 0; r < 4; ++r) {
                float v = sc0[t * 4 + r];
                #pragma unroll
                for (int off = 1; off <= 8; off <<= 1)
                    v = fminf(v, __shfl_xor(v, off, 16));
                if (jj == 0)
                    atomicMin((unsigned int*)&thrRow[t * 16 + g * 4 + r],
                              __float_as_uint(v + MARGIN));
            }
    }
    __syncthreads();   // thr = min-of-64 + MARGIN (also drains b1's stage)

    // collect iter-0 scores against the seeded thresholds
    {
        int kc0 = w * 16 + jj;
        #pragma unroll
        for (int t = 0; t < 4; ++t)
            #pragma unroll
            for (int r = 0; r < 4; ++r) {
                float sc = sc0[t * 4 + r];
                int row_ = t * 16 + g * 4 + r;
                if (sc <= thrRow[row_]) {
                    int p_ = atomicAdd(&cnt[row_], 1);
                    if (p_ < CAP) cand[row_][p_] = kc0;
                }
            }
    }

    // ---- main sweep: tiles j=1..63 (wave-private pipeline, no barriers) ----
    #pragma unroll 1
    for (int j = 1; j < 62; j += 2) {
        STAGE(b0, (j + 1) * 4 + w);
        COMPUTE(b1, j * 4 + w, "9");
        STAGE(b1, (j + 2) * 4 + w);
        COMPUTE(b0, (j + 1) * 4 + w, "9");
    }
    COMPUTE(b1, 63 * 4 + w, "0");       // final tile: drain
    __syncthreads();                    // cand/cnt visible; ebuf dead after this

#undef STAGE
#undef MFMADOT
#undef COLLECT1
#undef COMPUTE

    // ---- exact fp32 rescore of candidates (4 threads per row, 2-way ILP) ----
    const int crow = tid & 63;
    const int sub  = tid >> 6;
    unsigned long long best = ~0ULL;
    {
        int cc = cnt[crow];
        float rowA = A[rowBase + crow];
        const float* xsrow = x + (size_t)(rowBase + crow) * DIM;
        if (cc <= CAP) {
            int c = sub;
            for (; c + 4 < cc; c += 8) {
                unsigned long long pk = exact_pack2(emb, C, xsrow, rowA,
                                                   cand[crow][c], cand[crow][c + 4]);
                best = best < pk ? best : pk;
            }
            if (c < cc) {
                unsigned long long pk = exact_pack(emb, C, xsrow, rowA, cand[crow][c]);
                best = best < pk ? best : pk;
            }
        } else {
            // overflow fallback (rare): full exact row scan
            for (int k = sub; k < KCB; k += 8) {
                unsigned long long pk = exact_pack2(emb, C, xsrow, rowA, k, k + 4);
                best = best < pk ? best : pk;
            }
        }
    }
    sh.bestA[sub][crow] = best;          // ebuf/xstage dead; barrier above
    __syncthreads();
    if (tid < MROWS) {
        unsigned long long v0 = sh.bestA[0][tid], v1 = sh.bestA[1][tid];
        unsigned long long v2 = sh.bestA[2][tid], v3 = sh.bestA[3][tid];
        unsigned long long b = v0 < v1 ? v0 : v1;
        unsigned long long c2 = v2 < v3 ? v2 : v3;
        b = b < c2 ? b : c2;
        int idx = (int)(unsigned)(b & 0xFFFFFFFFull);
        sIdx[tid] = idx;
        out[1 + (size_t)N_TOK * DIM + rowBase + tid] = (float)idx;
    }
    __syncthreads();

    // ---- outputs: quantized gather (exact) + fp64 loss partial ----
    double lsum = 0.0;
    for (int row = 0; row < MROWS; ++row) {
        int idx = sIdx[row];
        float q  = emb[(size_t)idx * DIM + tid];
        float xv = x[(size_t)(rowBase + row) * DIM + tid];
        out[1 + (size_t)(rowBase + row) * DIM + tid] = q;
        double df = (double)q - (double)xv;
        lsum += df * df;
    }
    #pragma unroll
    for (int off = 1; off < 64; off <<= 1) lsum += __shfl_xor(lsum, off, 64);
    __syncthreads();
    if ((tid & 63) == 0) sRed[tid >> 6] = lsum;
    __syncthreads();
    if (tid == 0) atomicAdd(lossAcc, sRed[0] + sRed[1] + sRed[2] + sRed[3]);
}

// ---------------------------------------------------------------------------
// Legacy kernel (proven-passing), fallback if ws is too small.
__global__ __launch_bounds__(256, 2) void vq_np(
    const float* __restrict__ x, const float* __restrict__ emb,
    const float* __restrict__ A, const float* __restrict__ C,
    float* __restrict__ out, double* __restrict__ lossAcc)
{
    __shared__ float xs[MROWS][DIM];
    __shared__ float est[DC][ESD];
    __shared__ float sA[MROWS];
    __shared__ int   sIdx[MROWS];
    __shared__ double sRed[4];

    const int tid = threadIdx.x;
    const int c = tid & 31;
    const int r = tid >> 5;
    const int rowBase = blockIdx.x * MROWS;

    if (tid < MROWS) sA[tid] = A[rowBase + tid];

    #pragma unroll
    for (int p = 0; p < 16; ++p) {
        int flat = p * 256 + tid;
        int row = flat >> 6, d = (flat & 63) * 4;
        float4 v = *(const float4*)(x + (size_t)(rowBase + row) * DIM + d);
        *(float4*)&xs[row][d] = v;
    }

    float m1[8];
    int   i1[8];
    #pragma unroll
    for (int ri = 0; ri < 8; ++ri) { m1[ri] = 3.4e38f; i1[ri] = 0; }

    for (int kt = 0; kt < NKT; ++kt) {
        float acc[8][8];
        #pragma unroll
        for (int ri = 0; ri < 8; ++ri)
            #pragma unroll
            for (int kk = 0; kk < 8; ++kk) acc[ri][kk] = 0.f;

        for (int dc = 0; dc < NDC; ++dc) {
            const float* src = emb + (size_t)(kt * KT + tid) * DIM + dc * DC;
            float4 ea = *(const float4*)(src);
            float4 eb = *(const float4*)(src + 4);
            __syncthreads();
            est[0][tid] = ea.x; est[1][tid] = ea.y; est[2][tid] = ea.z; est[3][tid] = ea.w;
            est[4][tid] = eb.x; est[5][tid] = eb.y; est[6][tid] = eb.z; est[7][tid] = eb.w;
            __syncthreads();
            #pragma unroll
            for (int d4 = 0; d4 < 2; ++d4) {
                float4 xf[8];
                #pragma unroll
                for (int ri = 0; ri < 8; ++ri)
                    xf[ri] = *(const float4*)&xs[r * 8 + ri][dc * DC + d4 * 4];
                #pragma unroll
                for (int dd = 0; dd < 4; ++dd) {
                    float2 ev[4];
                    #pragma unroll
                    for (int j = 0; j < 4; ++j)
                        ev[j] = *(const float2*)&est[d4 * 4 + dd][2 * c + 64 * j];
                    #pragma unroll
                    for (int ri = 0; ri < 8; ++ri) {
                        float xv = (dd == 0) ? xf[ri].x : (dd == 1) ? xf[ri].y
                                 : (dd == 2) ? xf[ri].z : xf[ri].w;
                        #pragma unroll
                        for (int j = 0; j < 4; ++j) {
                            acc[ri][2 * j]     = fmaf(xv, ev[j].x, acc[ri][2 * j]);
                            acc[ri][2 * j + 1] = fmaf(xv, ev[j].y, acc[ri][2 * j + 1]);
                        }
                    }
                }
            }
        }
        #pragma unroll
        for (int j = 0; j < 4; ++j) {
            float2 Cv = *(const float2*)&C[kt * KT + 2 * c + 64 * j];
            #pragma unroll
            for (int p = 0; p < 2; ++p) {
                int kg = kt * KT + 2 * c + 64 * j + p;
                float Ck = (p == 0) ? Cv.x : Cv.y;
                #pragma unroll
                for (int ri = 0; ri < 8; ++ri) {
                    float tmp = sA[r * 8 + ri] - 2.0f * acc[ri][2 * j + p];
                    float s   = tmp + Ck;
                    if (s < m1[ri]) { m1[ri] = s; i1[ri] = kg; }
                }
            }
        }
    }

    #pragma unroll
    for (int ri = 0; ri < 8; ++ri) {
        float a = m1[ri]; int ja = i1[ri];
        #pragma unroll
        for (int off = 1; off <= 16; off <<= 1) {
            float b  = __shfl_xor(a, off, 64);
            int   jb = __shfl_xor(ja, off, 64);
            if (b < a || (b == a && jb < ja)) { a = b; ja = jb; }
        }
        if (c == 0) sIdx[r * 8 + ri] = ja;
    }
    __syncthreads();

    if (tid < MROWS) {
        out[1 + (size_t)N_TOK * DIM + rowBase + tid] = (float)sIdx[tid];
    }
    double lsum = 0.0;
    for (int row = 0; row < MROWS; ++row) {
        int idx = sIdx[row];
        float q  = emb[(size_t)idx * DIM + tid];
        float xv = xs[row][tid];
        out[1 + (size_t)(rowBase + row) * DIM + tid] = q;
        double df = (double)q - (double)xv;
        lsum += df * df;
    }
    #pragma unroll
    for (int off = 1; off < 64; off <<= 1) lsum += __shfl_xor(lsum, off, 64);
    __syncthreads();
    if ((tid & 63) == 0) sRed[tid >> 6] = lsum;
    __syncthreads();
    if (tid == 0) {
        atomicAdd(lossAcc, sRed[0] + sRed[1] + sRed[2] + sRed[3]);
    }
}

// ---------------------------------------------------------------------------
__global__ void finalize_kernel(const double* __restrict__ lossAcc, float* __restrict__ out) {
    out[0] = (float)(0.5 * (*lossAcc) / (double)((size_t)N_TOK * DIM));
}

extern "C" void kernel_launch(void* const* d_in, const int* in_sizes, int n_in,
                              void* d_out, int out_size, void* d_ws, size_t ws_size,
                              hipStream_t stream) {
    const float* x   = (const float*)d_in[0];   // [16,2048,256] fp32
    const float* emb = (const float*)d_in[1];   // [4096,256] fp32
    float* out = (float*)d_out;

    double* lossAcc = (double*)d_ws;
    float*  A       = (float*)((char*)d_ws + WS_A);
    float*  C       = (float*)((char*)d_ws + WS_C);
    unsigned char* etiles = (unsigned char*)((char*)d_ws + WS_E);

    const bool use_new = ws_size >= WS_NEED_NEW;

    hipMemsetAsync(d_ws, 0, 16, stream);
    xsq_np_kernel<<<N_TOK / 4, 256, 0, stream>>>(x, A);
    esq_np_kernel<<<KCB / 4, 256, 0, stream>>>(emb, C, use_new ? etiles : nullptr);
    if (use_new)
        vq_mfma<<<N_TOK / MROWS, 256, 0, stream>>>(x, emb, etiles, A, C, out, lossAcc);
    else
        vq_np<<<N_TOK / MROWS, 256, 0, stream>>>(x, emb, A, C, out, lossAcc);
    finalize_kernel<<<1, 1, 0, stream>>>(lossAcc, out);
}

// Round 9
// 263.413 us; speedup vs baseline: 41.8794x; 13.5695x over previous
//
#include <hip/hip_runtime.h>

#define N_TOK 32768
#define DIM   256
#define KCB   4096
#define MROWS 64           // rows per block
#define XSP   260          // padded xstage row stride (floats)
#define NTILE (KCB / 16)   // 256 code-tiles of 16 codes
#define TILE_B 8448        // 16*256*2 (bf16, swizzled) + 256 (C floats, 64B valid)
// ---- legacy-kernel tile params (fallback path) ----
#define KT    256
#define NKT   (KCB / KT)
#define DC    8
#define NDC   (DIM / DC)
#define ESD   258

// ws layout (bytes):
//   0      : double lossAcc (zeroed by 16B memset)
//   16     : float A[N_TOK]  -- numpy-replica fp32 ||x_i||^2
//   131088 : float C[KCB]    -- fp32 ||e_k||^2
//   147472 : etiles[256][8448] -- pre-swizzled bf16 code-tiles + appended C
#define WS_A 16
#define WS_C (16 + 4 * N_TOK)
#define WS_E (WS_C + 4 * KCB)
#define WS_NEED_NEW ((size_t)WS_E + (size_t)NTILE * TILE_B)

#define CAP    48          // candidate list capacity per row
#define MARGIN 1.5e-3f     // >= 2x worst-case bf16-approx score error (~5e-4 hard)
// Approx scores biased by +1.0f: sb = 1 + C - 2*dot in [~0.98, ~1.02] -> POSITIVE,
// so u32-bit atomicMin == float-min. Round-8 lesson: a min-of-64 seed leaves a
// ~0.1%/row loose-seed tail that burst-overflows CAP and triggers the ~3ms/row
// fallback (26 straggler blocks = 1.5% occupancy, 3.7ms). Fix: phase A seeds
// from 512 codes (min-only), phases B/C collect against the tight threshold.

typedef __attribute__((ext_vector_type(8))) short short8v;  // 8 x bf16 bits
typedef __attribute__((ext_vector_type(4))) float f32x4;

__device__ __forceinline__ unsigned short f2bf_rne(float f) {
    unsigned u = __float_as_uint(f);
    unsigned r = (u + 0x7FFFu + ((u >> 16) & 1u)) >> 16;
    return (unsigned short)r;
}

// async global->LDS staging helpers (size must be literal)
__device__ __forceinline__ void gld16(const void* g, void* l) {
    __builtin_amdgcn_global_load_lds(
        (const __attribute__((address_space(1))) unsigned int*)g,
        (__attribute__((address_space(3))) unsigned int*)l, 16, 0, 0);
}
__device__ __forceinline__ void gld4(const void* g, void* l) {
    __builtin_amdgcn_global_load_lds(
        (const __attribute__((address_space(1))) unsigned int*)g,
        (__attribute__((address_space(3))) unsigned int*)l, 4, 0, 0);
}

// ---------------------------------------------------------------------------
// Kernel A: bit-exact replica of numpy's fp32 pairwise row sum-of-squares.
__global__ __launch_bounds__(256) void xsq_np_kernel(const float* __restrict__ x,
                                                     float* __restrict__ A) {
#pragma clang fp contract(off)
    __shared__ float xr[4][256];
    const int tid = threadIdx.x;
    const int w = tid >> 6, l = tid & 63;
    const int row = blockIdx.x * 4 + w;
    float4 v = *(const float4*)(x + (size_t)row * DIM + l * 4);
    xr[w][l * 4 + 0] = v.x; xr[w][l * 4 + 1] = v.y;
    xr[w][l * 4 + 2] = v.z; xr[w][l * 4 + 3] = v.w;
    __syncthreads();
    const float* t = xr[w];
    const int g = (l >> 4) & 1;
    const int j = l & 15;
    const int base = g * 128 + j;
    float t0 = t[base +   0] * t[base +   0];
    float t1 = t[base +  16] * t[base +  16];
    float t2 = t[base +  32] * t[base +  32];
    float t3 = t[base +  48] * t[base +  48];
    float t4 = t[base +  64] * t[base +  64];
    float t5 = t[base +  80] * t[base +  80];
    float t6 = t[base +  96] * t[base +  96];
    float t7 = t[base + 112] * t[base + 112];
    float p = ((t0 + t1) + (t2 + t3)) + ((t4 + t5) + (t6 + t7));
    p = p + __shfl_xor(p, 8, 64);
    p = p + __shfl_xor(p, 4, 64);
    p = p + __shfl_xor(p, 2, 64);
    p = p + __shfl_xor(p, 1, 64);
    float other = __shfl(p, 16, 64);
    if (l == 0) A[row] = p + other;
}

// ---------------------------------------------------------------------------
// Kernel B: C[k] exact; also emits PRE-SWIZZLED bf16 tiles + appended C.
// Rotation swizzle: 16B unit u stored at u ^ f(jj), f(jj)=((jj>>1)&3)|((jj&1)<<2).
__global__ void esq_np_kernel(const float* __restrict__ emb, float* __restrict__ C,
                              unsigned char* __restrict__ etiles) {
#pragma clang fp contract(off)
    int row  = blockIdx.x * 4 + (threadIdx.x >> 6);
    int lane = threadIdx.x & 63;
    float4 v = *(const float4*)(emb + (size_t)row * DIM + lane * 4);
    int tile = row >> 4, jj = row & 15;
    if (etiles) {
        ushort4 h;
        h.x = f2bf_rne(v.x); h.y = f2bf_rne(v.y);
        h.z = f2bf_rne(v.z); h.w = f2bf_rne(v.w);
        int f  = ((jj >> 1) & 3) | ((jj & 1) << 2);
        int u  = jj * 32 + (lane >> 1);      // 16B unit within tile
        int qs = u ^ f;                      // swizzled unit (stays in row: f<8<32)
        *(ushort4*)(etiles + (size_t)tile * TILE_B + qs * 16 + (lane & 1) * 8) = h;
    }
    float s0 = v.x * v.x, s1 = v.y * v.y, s2 = v.z * v.z, s3 = v.w * v.w;
    double qd = (double)s0 + (double)s1 + (double)s2 + (double)s3;
    #pragma unroll
    for (int off = 32; off; off >>= 1) qd += __shfl_xor(qd, off, 64);
    if (lane == 0) {
        float cf = (float)qd;
        C[row] = cf;
        if (etiles)
            *(float*)(etiles + (size_t)tile * TILE_B + 8192 + jj * 4) = cf;
    }
}

// ---------------------------------------------------------------------------
// Exact fp32 score, bit-identical arithmetic to the proven-passing kernel.
__device__ __forceinline__ unsigned long long exact_pack(
    const float* __restrict__ emb, const float* __restrict__ C,
    const float* __restrict__ xsrow, float rowA, int k)
{
    const float4* er = (const float4*)(emb + (size_t)k * DIM);
    float acc = 0.f;
    #pragma unroll 8
    for (int d4 = 0; d4 < DIM / 4; ++d4) {
        float4 ev = er[d4];
        float4 xv = *(const float4*)(xsrow + d4 * 4);
        acc = fmaf(xv.x, ev.x, acc);
        acc = fmaf(xv.y, ev.y, acc);
        acc = fmaf(xv.z, ev.z, acc);
        acc = fmaf(xv.w, ev.w, acc);
    }
    float tmp = rowA - 2.0f * acc;
    float sc  = tmp + C[k];
    // exact scores are squared distances (positive): bit pattern is monotone
    return ((unsigned long long)__float_as_uint(sc) << 32) | (unsigned)k;
}

// Two candidates interleaved (independent fmaf chains -> 2x ILP).
__device__ __forceinline__ unsigned long long exact_pack2(
    const float* __restrict__ emb, const float* __restrict__ C,
    const float* __restrict__ xsrow, float rowA, int k1, int k2)
{
    const float4* e1 = (const float4*)(emb + (size_t)k1 * DIM);
    const float4* e2 = (const float4*)(emb + (size_t)k2 * DIM);
    float a1 = 0.f, a2 = 0.f;
    #pragma unroll 8
    for (int d4 = 0; d4 < DIM / 4; ++d4) {
        float4 xv = *(const float4*)(xsrow + d4 * 4);
        float4 v1 = e1[d4];
        float4 v2 = e2[d4];
        a1 = fmaf(xv.x, v1.x, a1);  a2 = fmaf(xv.x, v2.x, a2);
        a1 = fmaf(xv.y, v1.y, a1);  a2 = fmaf(xv.y, v2.y, a2);
        a1 = fmaf(xv.z, v1.z, a1);  a2 = fmaf(xv.z, v2.z, a2);
        a1 = fmaf(xv.w, v1.w, a1);  a2 = fmaf(xv.w, v2.w, a2);
    }
    float s1 = (rowA - 2.0f * a1) + C[k1];
    float s2 = (rowA - 2.0f * a2) + C[k2];
    unsigned long long p1 = ((unsigned long long)__float_as_uint(s1) << 32) | (unsigned)k1;
    unsigned long long p2 = ((unsigned long long)__float_as_uint(s2) << 32) | (unsigned)k2;
    return p1 < p2 ? p1 : p2;
}

// ---------------------------------------------------------------------------
// Kernel C: single bf16-MFMA sweep in 3 phases.
//   A (tiles 0..7/wave, 512 codes): min-only into registers -> seed thrRow.
//   B (tiles 8..63/wave): collect vs monotone LDS threshold (atomicMin bits).
//   C (re-run tiles 0..7/wave, +12.5% MFMA): collect phase-A codes vs final thr.
// Threshold invariant: thrRow >= sc_min + MARGIN always (updates write
// observed-sc + MARGIN, atomicMin on positive-float bits = float-min), so a
// stale read only over-collects. CAP-overflow -> exact row scan (insurance).
__global__ __launch_bounds__(256, 2) void vq_mfma(
    const float* __restrict__ x, const float* __restrict__ emb,
    const unsigned char* __restrict__ etiles,
    const float* __restrict__ A, const float* __restrict__ C,
    float* __restrict__ out, double* __restrict__ lossAcc)
{
    __shared__ union {
        float xstage[MROWS][XSP];                 // 66560 B (prologue only)
        unsigned char ebuf[4][2][TILE_B];         // 67584 B (sweep: per-wave dbuf)
        unsigned long long bestA[4][MROWS];       // 2048 B (post-sweep only)
    } sh;
    __shared__ int    cand[MROWS][CAP];           // 12288
    __shared__ int    cnt[MROWS];
    __shared__ float  thrRow[MROWS];              // monotone threshold (atomicMin bits)
    __shared__ int    sIdx[MROWS];
    __shared__ double sRed[4];

    const int tid = threadIdx.x;
    const int w   = tid >> 6;        // wave 0..3 (owns code-tiles j*4+w)
    const int l   = tid & 63;
    const int jj  = l & 15;          // MFMA col lane (code within tile)
    const int g   = l >> 4;          // MFMA k-group / D row group
    const int rowBase = blockIdx.x * MROWS;

    // ---- stage x tile into (padded) LDS for the frag build ----
    #pragma unroll
    for (int p = 0; p < 16; ++p) {
        int flat = p * 256 + tid;
        int row = flat >> 6, d = (flat & 63) * 4;
        *(float4*)&sh.xstage[row][d] = *(const float4*)(x + (size_t)(rowBase + row) * DIM + d);
    }
    if (tid < MROWS) { cnt[tid] = 0; thrRow[tid] = 3.4e38f; }
    __syncthreads();

    // ---- build all A fragments: 4 row-tiles x 8 k-steps (128 regs) ----
    short8v Af[4][8];
    #pragma unroll
    for (int t = 0; t < 4; ++t)
        #pragma unroll
        for (int s = 0; s < 8; ++s) {
            const float* xp = &sh.xstage[t * 16 + jj][s * 32 + g * 8];
            float4 a = *(const float4*)xp;
            float4 b = *(const float4*)(xp + 4);
            short8v f;
            f[0] = (short)f2bf_rne(a.x); f[1] = (short)f2bf_rne(a.y);
            f[2] = (short)f2bf_rne(a.z); f[3] = (short)f2bf_rne(a.w);
            f[4] = (short)f2bf_rne(b.x); f[5] = (short)f2bf_rne(b.y);
            f[6] = (short)f2bf_rne(b.z); f[7] = (short)f2bf_rne(b.w);
            Af[t][s] = f;
        }
    __syncthreads();   // all waves done reading xstage before ebuf overwrite

    // swizzled per-lane B-frag byte offsets (constant over tiles)
    const int fsw = ((jj >> 1) & 3) | ((jj & 1) << 2);
    int boff[8];
    #pragma unroll
    for (int s = 0; s < 8; ++s)
        boff[s] = ((jj * 32 + s * 4 + g) ^ fsw) * 16;

    unsigned char* b0 = sh.ebuf[w][0];
    unsigned char* b1 = sh.ebuf[w][1];

#define NTOF(JV) ((((JV) & 63) * 4) + w)

    // STAGE: 9 async global->LDS ops for tile NT into BUF (wave-private)
#define STAGE(BUF, NT)                                                        \
    {                                                                         \
        const unsigned char* src_ = etiles + (size_t)(NT) * TILE_B;           \
        _Pragma("unroll")                                                     \
        for (int j_ = 0; j_ < 8; ++j_)                                        \
            gld16(src_ + j_ * 1024 + l * 16, (BUF) + j_ * 1024);              \
        gld4(src_ + 8192 + l * 4, (BUF) + 8192);                              \
    }

    // MFMADOT: waits (counted), 32 MFMA on BUF -> acc0..acc3; CvB = 1 + C
#define MFMADOT(BUF, WAITN)                                                   \
        asm volatile("s_waitcnt vmcnt(" WAITN ")" ::: "memory");              \
        float CvB = 1.0f + *(const float*)((BUF) + 8192 + jj * 4);            \
        f32x4 acc0 = {0,0,0,0}, acc1 = {0,0,0,0};                             \
        f32x4 acc2 = {0,0,0,0}, acc3 = {0,0,0,0};                             \
        __builtin_amdgcn_s_setprio(1);                                        \
        _Pragma("unroll")                                                     \
        for (int s_ = 0; s_ < 8; ++s_) {                                      \
            short8v B_ = *(const short8v*)((BUF) + boff[s_]);                 \
            acc0 = __builtin_amdgcn_mfma_f32_16x16x32_bf16(Af[0][s_], B_, acc0, 0, 0, 0); \
            acc1 = __builtin_amdgcn_mfma_f32_16x16x32_bf16(Af[1][s_], B_, acc1, 0, 0, 0); \
            acc2 = __builtin_amdgcn_mfma_f32_16x16x32_bf16(Af[2][s_], B_, acc2, 0, 0, 0); \
            acc3 = __builtin_amdgcn_mfma_f32_16x16x32_bf16(Af[3][s_], B_, acc3, 0, 0, 0); \
        }                                                                     \
        __builtin_amdgcn_s_setprio(0);

    // MINC: phase-A tile -> register mins only (no LDS traffic, no atomics)
#define MINC(BUF)                                                             \
    {                                                                         \
        MFMADOT(BUF, "9")                                                     \
        _Pragma("unroll")                                                     \
        for (int r_ = 0; r_ < 4; ++r_) {                                      \
            amin[0][r_] = fminf(amin[0][r_], fmaf(-2.f, acc0[r_], CvB));      \
            amin[1][r_] = fminf(amin[1][r_], fmaf(-2.f, acc1[r_], CvB));      \
            amin[2][r_] = fminf(amin[2][r_], fmaf(-2.f, acc2[r_], CvB));      \
            amin[3][r_] = fminf(amin[3][r_], fmaf(-2.f, acc3[r_], CvB));      \
        }                                                                     \
    }

    // COLLECT1: threshold test + candidate append + monotone thr tighten.
    // Stale thrv only over-collects (actual thr <= stale thr). SC positive.
#define COLLECT1(SC, T, R)                                                    \
            if ((SC) <= thrv[T][R]) {                                         \
                int row_ = (T) * 16 + g * 4 + (R);                            \
                int p_ = atomicAdd(&cnt[row_], 1);                            \
                if (p_ < CAP) cand[row_][p_] = kc_;                           \
                if ((SC) + MARGIN < thrv[T][R])                               \
                    atomicMin((unsigned int*)&thrRow[row_],                   \
                              __float_as_uint((SC) + MARGIN));                \
            }

    // COMPUTE: MFMADOT + fresh thr load (post-MFMA) + collection for tile NT
#define COMPUTE(BUF, NT, WAITN)                                               \
    {                                                                         \
        MFMADOT(BUF, WAITN)                                                   \
        float4 thrv[4];                                                       \
        _Pragma("unroll")                                                     \
        for (int t_ = 0; t_ < 4; ++t_)                                        \
            thrv[t_] = *(const float4*)&thrRow[t_ * 16 + g * 4];              \
        int kc_ = (NT) * 16 + jj;                                             \
        _Pragma("unroll")                                                     \
        for (int r_ = 0; r_ < 4; ++r_) {                                      \
            float s0_ = fmaf(-2.f, acc0[r_], CvB);                            \
            float s1_ = fmaf(-2.f, acc1[r_], CvB);                            \
            float s2_ = fmaf(-2.f, acc2[r_], CvB);                            \
            float s3_ = fmaf(-2.f, acc3[r_], CvB);                            \
            COLLECT1(s0_, 0, r_)                                              \
            COLLECT1(s1_, 1, r_)                                              \
            COLLECT1(s2_, 2, r_)                                              \
            COLLECT1(s3_, 3, r_)                                              \
        }                                                                     \
    }

    // ---- phase A: tiles jv=0..7 per wave, min-only (512 codes block-wide) ----
    float amin[4][4];
    #pragma unroll
    for (int t = 0; t < 4; ++t)
        #pragma unroll
        for (int r = 0; r < 4; ++r) amin[t][r] = 3.4e38f;

    STAGE(b0, NTOF(0));
    STAGE(b1, NTOF(1));
    #pragma unroll 1
    for (int ja = 0; ja < 8; ja += 2) {
        MINC(b0)
        STAGE(b0, NTOF(ja + 2));      // ja=6 pre-stages NTOF(8) for phase B
        MINC(b1)
        STAGE(b1, NTOF(ja + 3));      // ja=6 pre-stages NTOF(9)
    }

    // seed thrRow = min-of-512 + MARGIN (reduce 16 lanes, atomicMin x 4 waves)
    #pragma unroll
    for (int t = 0; t < 4; ++t)
        #pragma unroll
        for (int r = 0; r < 4; ++r) {
            float v = amin[t][r];
            #pragma unroll
            for (int off = 1; off <= 8; off <<= 1)
                v = fminf(v, __shfl_xor(v, off, 16));
            if (jj == 0)
                atomicMin((unsigned int*)&thrRow[t * 16 + g * 4 + r],
                          __float_as_uint(v + MARGIN));
        }
    __syncthreads();   // thr visible to all waves (drains vmcnt; b0/b1 complete)

    // ---- phases B+C: tiles jv=8..63 (collect) then 64..71 (re-run A-tiles) ----
    #pragma unroll 1
    for (int jv = 8; jv < 70; jv += 2) {
        COMPUTE(b0, NTOF(jv), "9");
        STAGE(b0, NTOF(jv + 2));
        COMPUTE(b1, NTOF(jv + 1), "9");
        STAGE(b1, NTOF(jv + 3));      // jv=68 stages NTOF(70)/NTOF(71)
    }
    COMPUTE(b0, NTOF(70), "9");
    COMPUTE(b1, NTOF(71), "0");       // final: drain
    __syncthreads();                  // cand/cnt visible; ebuf dead after this

#undef NTOF
#undef STAGE
#undef MFMADOT
#undef MINC
#undef COLLECT1
#undef COMPUTE

    // ---- exact fp32 rescore of candidates (4 threads per row, 2-way ILP) ----
    const int crow = tid & 63;
    const int sub  = tid >> 6;
    unsigned long long best = ~0ULL;
    {
        int cc = cnt[crow];
        float rowA = A[rowBase + crow];
        const float* xsrow = x + (size_t)(rowBase + crow) * DIM;
        if (cc <= CAP) {
            int c = sub;
            for (; c + 4 < cc; c += 8) {
                unsigned long long pk = exact_pack2(emb, C, xsrow, rowA,
                                                   cand[crow][c], cand[crow][c + 4]);
                best = best < pk ? best : pk;
            }
            if (c < cc) {
                unsigned long long pk = exact_pack(emb, C, xsrow, rowA, cand[crow][c]);
                best = best < pk ? best : pk;
            }
        } else {
            // overflow fallback (P ~ 1e-4/run with 512-code seed): exact row scan
            for (int k = sub; k < KCB; k += 8) {
                unsigned long long pk = exact_pack2(emb, C, xsrow, rowA, k, k + 4);
                best = best < pk ? best : pk;
            }
        }
    }
    sh.bestA[sub][crow] = best;          // ebuf/xstage dead; barrier above
    __syncthreads();
    if (tid < MROWS) {
        unsigned long long v0 = sh.bestA[0][tid], v1 = sh.bestA[1][tid];
        unsigned long long v2 = sh.bestA[2][tid], v3 = sh.bestA[3][tid];
        unsigned long long b = v0 < v1 ? v0 : v1;
        unsigned long long c2 = v2 < v3 ? v2 : v3;
        b = b < c2 ? b : c2;
        int idx = (int)(unsigned)(b & 0xFFFFFFFFull);
        sIdx[tid] = idx;
        out[1 + (size_t)N_TOK * DIM + rowBase + tid] = (float)idx;
    }
    __syncthreads();

    // ---- outputs: quantized gather (exact) + fp64 loss partial ----
    double lsum = 0.0;
    for (int row = 0; row < MROWS; ++row) {
        int idx = sIdx[row];
        float q  = emb[(size_t)idx * DIM + tid];
        float xv = x[(size_t)(rowBase + row) * DIM + tid];
        out[1 + (size_t)(rowBase + row) * DIM + tid] = q;
        double df = (double)q - (double)xv;
        lsum += df * df;
    }
    #pragma unroll
    for (int off = 1; off < 64; off <<= 1) lsum += __shfl_xor(lsum, off, 64);
    __syncthreads();
    if ((tid & 63) == 0) sRed[tid >> 6] = lsum;
    __syncthreads();
    if (tid == 0) atomicAdd(lossAcc, sRed[0] + sRed[1] + sRed[2] + sRed[3]);
}

// ---------------------------------------------------------------------------
// Legacy kernel (proven-passing), fallback if ws is too small.
__global__ __launch_bounds__(256, 2) void vq_np(
    const float* __restrict__ x, const float* __restrict__ emb,
    const float* __restrict__ A, const float* __restrict__ C,
    float* __restrict__ out, double* __restrict__ lossAcc)
{
    __shared__ float xs[MROWS][DIM];
    __shared__ float est[DC][ESD];
    __shared__ float sA[MROWS];
    __shared__ int   sIdx[MROWS];
    __shared__ double sRed[4];

    const int tid = threadIdx.x;
    const int c = tid & 31;
    const int r = tid >> 5;
    const int rowBase = blockIdx.x * MROWS;

    if (tid < MROWS) sA[tid] = A[rowBase + tid];

    #pragma unroll
    for (int p = 0; p < 16; ++p) {
        int flat = p * 256 + tid;
        int row = flat >> 6, d = (flat & 63) * 4;
        float4 v = *(const float4*)(x + (size_t)(rowBase + row) * DIM + d);
        *(float4*)&xs[row][d] = v;
    }

    float m1[8];
    int   i1[8];
    #pragma unroll
    for (int ri = 0; ri < 8; ++ri) { m1[ri] = 3.4e38f; i1[ri] = 0; }

    for (int kt = 0; kt < NKT; ++kt) {
        float acc[8][8];
        #pragma unroll
        for (int ri = 0; ri < 8; ++ri)
            #pragma unroll
            for (int kk = 0; kk < 8; ++kk) acc[ri][kk] = 0.f;

        for (int dc = 0; dc < NDC; ++dc) {
            const float* src = emb + (size_t)(kt * KT + tid) * DIM + dc * DC;
            float4 ea = *(const float4*)(src);
            float4 eb = *(const float4*)(src + 4);
            __syncthreads();
            est[0][tid] = ea.x; est[1][tid] = ea.y; est[2][tid] = ea.z; est[3][tid] = ea.w;
            est[4][tid] = eb.x; est[5][tid] = eb.y; est[6][tid] = eb.z; est[7][tid] = eb.w;
            __syncthreads();
            #pragma unroll
            for (int d4 = 0; d4 < 2; ++d4) {
                float4 xf[8];
                #pragma unroll
                for (int ri = 0; ri < 8; ++ri)
                    xf[ri] = *(const float4*)&xs[r * 8 + ri][dc * DC + d4 * 4];
                #pragma unroll
                for (int dd = 0; dd < 4; ++dd) {
                    float2 ev[4];
                    #pragma unroll
                    for (int j = 0; j < 4; ++j)
                        ev[j] = *(const float2*)&est[d4 * 4 + dd][2 * c + 64 * j];
                    #pragma unroll
                    for (int ri = 0; ri < 8; ++ri) {
                        float xv = (dd == 0) ? xf[ri].x : (dd == 1) ? xf[ri].y
                                 : (dd == 2) ? xf[ri].z : xf[ri].w;
                        #pragma unroll
                        for (int j = 0; j < 4; ++j) {
                            acc[ri][2 * j]     = fmaf(xv, ev[j].x, acc[ri][2 * j]);
                            acc[ri][2 * j + 1] = fmaf(xv, ev[j].y, acc[ri][2 * j + 1]);
                        }
                    }
                }
            }
        }
        #pragma unroll
        for (int j = 0; j < 4; ++j) {
            float2 Cv = *(const float2*)&C[kt * KT + 2 * c + 64 * j];
            #pragma unroll
            for (int p = 0; p < 2; ++p) {
                int kg = kt * KT + 2 * c + 64 * j + p;
                float Ck = (p == 0) ? Cv.x : Cv.y;
                #pragma unroll
                for (int ri = 0; ri < 8; ++ri) {
                    float tmp = sA[r * 8 + ri] - 2.0f * acc[ri][2 * j + p];
                    float s   = tmp + Ck;
                    if (s < m1[ri]) { m1[ri] = s; i1[ri] = kg; }
                }
            }
        }
    }

    #pragma unroll
    for (int ri = 0; ri < 8; ++ri) {
        float a = m1[ri]; int ja = i1[ri];
        #pragma unroll
        for (int off = 1; off <= 16; off <<= 1) {
            float b  = __shfl_xor(a, off, 64);
            int   jb = __shfl_xor(ja, off, 64);
            if (b < a || (b == a && jb < ja)) { a = b; ja = jb; }
        }
        if (c == 0) sIdx[r * 8 + ri] = ja;
    }
    __syncthreads();

    if (tid < MROWS) {
        out[1 + (size_t)N_TOK * DIM + rowBase + tid] = (float)sIdx[tid];
    }
    double lsum = 0.0;
    for (int row = 0; row < MROWS; ++row) {
        int idx = sIdx[row];
        float q  = emb[(size_t)idx * DIM + tid];
        float xv = xs[row][tid];
        out[1 + (size_t)(rowBase + row) * DIM + tid] = q;
        double df = (double)q - (double)xv;
        lsum += df * df;
    }
    #pragma unroll
    for (int off = 1; off < 64; off <<= 1) lsum += __shfl_xor(lsum, off, 64);
    __syncthreads();
    if ((tid & 63) == 0) sRed[tid >> 6] = lsum;
    __syncthreads();
    if (tid == 0) {
        atomicAdd(lossAcc, sRed[0] + sRed[1] + sRed[2] + sRed[3]);
    }
}

// ---------------------------------------------------------------------------
__global__ void finalize_kernel(const double* __restrict__ lossAcc, float* __restrict__ out) {
    out[0] = (float)(0.5 * (*lossAcc) / (double)((size_t)N_TOK * DIM));
}

extern "C" void kernel_launch(void* const* d_in, const int* in_sizes, int n_in,
                              void* d_out, int out_size, void* d_ws, size_t ws_size,
                              hipStream_t stream) {
    const float* x   = (const float*)d_in[0];   // [16,2048,256] fp32
    const float* emb = (const float*)d_in[1];   // [4096,256] fp32
    float* out = (float*)d_out;

    double* lossAcc = (double*)d_ws;
    float*  A       = (float*)((char*)d_ws + WS_A);
    float*  C       = (float*)((char*)d_ws + WS_C);
    unsigned char* etiles = (unsigned char*)((char*)d_ws + WS_E);

    const bool use_new = ws_size >= WS_NEED_NEW;

    hipMemsetAsync(d_ws, 0, 16, stream);
    xsq_np_kernel<<<N_TOK / 4, 256, 0, stream>>>(x, A);
    esq_np_kernel<<<KCB / 4, 256, 0, stream>>>(emb, C, use_new ? etiles : nullptr);
    if (use_new)
        vq_mfma<<<N_TOK / MROWS, 256, 0, stream>>>(x, emb, etiles, A, C, out, lossAcc);
    else
        vq_np<<<N_TOK / MROWS, 256, 0, stream>>>(x, emb, A, C, out, lossAcc);
    finalize_kernel<<<1, 1, 0, stream>>>(lossAcc, out);
}

// Round 10
// 258.402 us; speedup vs baseline: 42.6917x; 1.0194x over previous
//
#include <hip/hip_runtime.h>

#define N_TOK 32768
#define DIM   256
#define KCB   4096
#define MROWS 64           // rows per block
#define XSP   260          // padded xstage row stride (floats)
#define NTILE (KCB / 16)   // 256 code-tiles of 16 codes
#define TILE_B 8448        // 16*256*2 (bf16, swizzled) + 256 (C floats, 64B valid)
// ---- legacy-kernel tile params (fallback path) ----
#define KT    256
#define NKT   (KCB / KT)
#define DC    8
#define NDC   (DIM / DC)
#define ESD   258

// ws layout (bytes):
//   0      : double lossAcc (zeroed by 16B memset)
//   16     : float A[N_TOK]  -- numpy-replica fp32 ||x_i||^2
//   131088 : float C[KCB]    -- fp32 ||e_k||^2
//   147472 : etiles[256][8448] -- pre-swizzled bf16 code-tiles + appended C
#define WS_A 16
#define WS_C (16 + 4 * N_TOK)
#define WS_E (WS_C + 4 * KCB)
#define WS_NEED_NEW ((size_t)WS_E + (size_t)NTILE * TILE_B)

#define CAP    48          // candidate list capacity per row
#define MARGIN 1.5e-3f     // >= 2x worst-case bf16-approx score error (~5e-4 hard)
// Approx scores biased by +1.0f -> POSITIVE -> u32-bit atomicMin == float-min.
// r8 lesson: min-of-64 seed leaves a loose-seed tail -> phase A seeds from 512.
// r9 lesson: 16 separate branchy collect sites cost ~5K cyc/tile (collect-tile
// 6.7K vs min-tile 1.46K by r3/r9 cross-solve) -> branchless 16-bit mask +
// single compact slow path (~2 iterations when taken).

typedef __attribute__((ext_vector_type(8))) short short8v;  // 8 x bf16 bits
typedef __attribute__((ext_vector_type(4))) float f32x4;

__device__ __forceinline__ unsigned short f2bf_rne(float f) {
    unsigned u = __float_as_uint(f);
    unsigned r = (u + 0x7FFFu + ((u >> 16) & 1u)) >> 16;
    return (unsigned short)r;
}

// async global->LDS staging helpers (size must be literal)
__device__ __forceinline__ void gld16(const void* g, void* l) {
    __builtin_amdgcn_global_load_lds(
        (const __attribute__((address_space(1))) unsigned int*)g,
        (__attribute__((address_space(3))) unsigned int*)l, 16, 0, 0);
}
__device__ __forceinline__ void gld4(const void* g, void* l) {
    __builtin_amdgcn_global_load_lds(
        (const __attribute__((address_space(1))) unsigned int*)g,
        (__attribute__((address_space(3))) unsigned int*)l, 4, 0, 0);
}

// ---------------------------------------------------------------------------
// Kernel A: bit-exact replica of numpy's fp32 pairwise row sum-of-squares.
__global__ __launch_bounds__(256) void xsq_np_kernel(const float* __restrict__ x,
                                                     float* __restrict__ A) {
#pragma clang fp contract(off)
    __shared__ float xr[4][256];
    const int tid = threadIdx.x;
    const int w = tid >> 6, l = tid & 63;
    const int row = blockIdx.x * 4 + w;
    float4 v = *(const float4*)(x + (size_t)row * DIM + l * 4);
    xr[w][l * 4 + 0] = v.x; xr[w][l * 4 + 1] = v.y;
    xr[w][l * 4 + 2] = v.z; xr[w][l * 4 + 3] = v.w;
    __syncthreads();
    const float* t = xr[w];
    const int g = (l >> 4) & 1;
    const int j = l & 15;
    const int base = g * 128 + j;
    float t0 = t[base +   0] * t[base +   0];
    float t1 = t[base +  16] * t[base +  16];
    float t2 = t[base +  32] * t[base +  32];
    float t3 = t[base +  48] * t[base +  48];
    float t4 = t[base +  64] * t[base +  64];
    float t5 = t[base +  80] * t[base +  80];
    float t6 = t[base +  96] * t[base +  96];
    float t7 = t[base + 112] * t[base + 112];
    float p = ((t0 + t1) + (t2 + t3)) + ((t4 + t5) + (t6 + t7));
    p = p + __shfl_xor(p, 8, 64);
    p = p + __shfl_xor(p, 4, 64);
    p = p + __shfl_xor(p, 2, 64);
    p = p + __shfl_xor(p, 1, 64);
    float other = __shfl(p, 16, 64);
    if (l == 0) A[row] = p + other;
}

// ---------------------------------------------------------------------------
// Kernel B: C[k] exact; also emits PRE-SWIZZLED bf16 tiles + appended C.
// Rotation swizzle: 16B unit u stored at u ^ f(jj), f(jj)=((jj>>1)&3)|((jj&1)<<2).
__global__ void esq_np_kernel(const float* __restrict__ emb, float* __restrict__ C,
                              unsigned char* __restrict__ etiles) {
#pragma clang fp contract(off)
    int row  = blockIdx.x * 4 + (threadIdx.x >> 6);
    int lane = threadIdx.x & 63;
    float4 v = *(const float4*)(emb + (size_t)row * DIM + lane * 4);
    int tile = row >> 4, jj = row & 15;
    if (etiles) {
        ushort4 h;
        h.x = f2bf_rne(v.x); h.y = f2bf_rne(v.y);
        h.z = f2bf_rne(v.z); h.w = f2bf_rne(v.w);
        int f  = ((jj >> 1) & 3) | ((jj & 1) << 2);
        int u  = jj * 32 + (lane >> 1);      // 16B unit within tile
        int qs = u ^ f;                      // swizzled unit (stays in row: f<8<32)
        *(ushort4*)(etiles + (size_t)tile * TILE_B + qs * 16 + (lane & 1) * 8) = h;
    }
    float s0 = v.x * v.x, s1 = v.y * v.y, s2 = v.z * v.z, s3 = v.w * v.w;
    double qd = (double)s0 + (double)s1 + (double)s2 + (double)s3;
    #pragma unroll
    for (int off = 32; off; off >>= 1) qd += __shfl_xor(qd, off, 64);
    if (lane == 0) {
        float cf = (float)qd;
        C[row] = cf;
        if (etiles)
            *(float*)(etiles + (size_t)tile * TILE_B + 8192 + jj * 4) = cf;
    }
}

// ---------------------------------------------------------------------------
// Exact fp32 score, bit-identical arithmetic to the proven-passing kernel.
__device__ __forceinline__ unsigned long long exact_pack(
    const float* __restrict__ emb, const float* __restrict__ C,
    const float* __restrict__ xsrow, float rowA, int k)
{
    const float4* er = (const float4*)(emb + (size_t)k * DIM);
    float acc = 0.f;
    #pragma unroll 8
    for (int d4 = 0; d4 < DIM / 4; ++d4) {
        float4 ev = er[d4];
        float4 xv = *(const float4*)(xsrow + d4 * 4);
        acc = fmaf(xv.x, ev.x, acc);
        acc = fmaf(xv.y, ev.y, acc);
        acc = fmaf(xv.z, ev.z, acc);
        acc = fmaf(xv.w, ev.w, acc);
    }
    float tmp = rowA - 2.0f * acc;
    float sc  = tmp + C[k];
    // exact scores are squared distances (positive): bit pattern is monotone
    return ((unsigned long long)__float_as_uint(sc) << 32) | (unsigned)k;
}

// Two candidates interleaved (independent fmaf chains -> 2x ILP).
__device__ __forceinline__ unsigned long long exact_pack2(
    const float* __restrict__ emb, const float* __restrict__ C,
    const float* __restrict__ xsrow, float rowA, int k1, int k2)
{
    const float4* e1 = (const float4*)(emb + (size_t)k1 * DIM);
    const float4* e2 = (const float4*)(emb + (size_t)k2 * DIM);
    float a1 = 0.f, a2 = 0.f;
    #pragma unroll 8
    for (int d4 = 0; d4 < DIM / 4; ++d4) {
        float4 xv = *(const float4*)(xsrow + d4 * 4);
        float4 v1 = e1[d4];
        float4 v2 = e2[d4];
        a1 = fmaf(xv.x, v1.x, a1);  a2 = fmaf(xv.x, v2.x, a2);
        a1 = fmaf(xv.y, v1.y, a1);  a2 = fmaf(xv.y, v2.y, a2);
        a1 = fmaf(xv.z, v1.z, a1);  a2 = fmaf(xv.z, v2.z, a2);
        a1 = fmaf(xv.w, v1.w, a1);  a2 = fmaf(xv.w, v2.w, a2);
    }
    float s1 = (rowA - 2.0f * a1) + C[k1];
    float s2 = (rowA - 2.0f * a2) + C[k2];
    unsigned long long p1 = ((unsigned long long)__float_as_uint(s1) << 32) | (unsigned)k1;
    unsigned long long p2 = ((unsigned long long)__float_as_uint(s2) << 32) | (unsigned)k2;
    return p1 < p2 ? p1 : p2;
}

// ---------------------------------------------------------------------------
// Kernel C: single bf16-MFMA sweep in 3 phases (A: seed min-of-512; B: collect;
// C: re-run A-tiles vs final thr). Collection is branchless-mask + one compact
// slow path. Threshold invariant: thrRow >= sc_min + MARGIN always (atomicMin
// on positive-float bits = float-min); stale thrv only over-collects.
// CAP-overflow -> exact row scan (insurance).
__global__ __launch_bounds__(256, 2) void vq_mfma(
    const float* __restrict__ x, const float* __restrict__ emb,
    const unsigned char* __restrict__ etiles,
    const float* __restrict__ A, const float* __restrict__ C,
    float* __restrict__ out, double* __restrict__ lossAcc)
{
    __shared__ union {
        float xstage[MROWS][XSP];                 // 66560 B (prologue only)
        unsigned char ebuf[4][2][TILE_B];         // 67584 B (sweep: per-wave dbuf)
        unsigned long long bestA[4][MROWS];       // 2048 B (post-sweep only)
    } sh;
    __shared__ int    cand[MROWS][CAP];           // 12288
    __shared__ int    cnt[MROWS];
    __shared__ float  thrRow[MROWS];              // monotone threshold (atomicMin bits)
    __shared__ int    sIdx[MROWS];
    __shared__ double sRed[4];

    const int tid = threadIdx.x;
    const int w   = tid >> 6;        // wave 0..3 (owns code-tiles j*4+w)
    const int l   = tid & 63;
    const int jj  = l & 15;          // MFMA col lane (code within tile)
    const int g   = l >> 4;          // MFMA k-group / D row group
    const int rowBase = blockIdx.x * MROWS;

    // ---- stage x tile into (padded) LDS for the frag build ----
    #pragma unroll
    for (int p = 0; p < 16; ++p) {
        int flat = p * 256 + tid;
        int row = flat >> 6, d = (flat & 63) * 4;
        *(float4*)&sh.xstage[row][d] = *(const float4*)(x + (size_t)(rowBase + row) * DIM + d);
    }
    if (tid < MROWS) { cnt[tid] = 0; thrRow[tid] = 3.4e38f; }
    __syncthreads();

    // ---- build all A fragments: 4 row-tiles x 8 k-steps (128 regs) ----
    short8v Af[4][8];
    #pragma unroll
    for (int t = 0; t < 4; ++t)
        #pragma unroll
        for (int s = 0; s < 8; ++s) {
            const float* xp = &sh.xstage[t * 16 + jj][s * 32 + g * 8];
            float4 a = *(const float4*)xp;
            float4 b = *(const float4*)(xp + 4);
            short8v f;
            f[0] = (short)f2bf_rne(a.x); f[1] = (short)f2bf_rne(a.y);
            f[2] = (short)f2bf_rne(a.z); f[3] = (short)f2bf_rne(a.w);
            f[4] = (short)f2bf_rne(b.x); f[5] = (short)f2bf_rne(b.y);
            f[6] = (short)f2bf_rne(b.z); f[7] = (short)f2bf_rne(b.w);
            Af[t][s] = f;
        }
    __syncthreads();   // all waves done reading xstage before ebuf overwrite

    // swizzled per-lane B-frag byte offsets (constant over tiles)
    const int fsw = ((jj >> 1) & 3) | ((jj & 1) << 2);
    int boff[8];
    #pragma unroll
    for (int s = 0; s < 8; ++s)
        boff[s] = ((jj * 32 + s * 4 + g) ^ fsw) * 16;

    unsigned char* b0 = sh.ebuf[w][0];
    unsigned char* b1 = sh.ebuf[w][1];

#define NTOF(JV) ((((JV) & 63) * 4) + w)

    // STAGE: 9 async global->LDS ops for tile NT into BUF (wave-private)
#define STAGE(BUF, NT)                                                        \
    {                                                                         \
        const unsigned char* src_ = etiles + (size_t)(NT) * TILE_B;           \
        _Pragma("unroll")                                                     \
        for (int j_ = 0; j_ < 8; ++j_)                                        \
            gld16(src_ + j_ * 1024 + l * 16, (BUF) + j_ * 1024);              \
        gld4(src_ + 8192 + l * 4, (BUF) + 8192);                              \
    }

    // MFMADOT: waits (counted), 32 MFMA on BUF -> acc0..acc3; CvB = 1 + C
#define MFMADOT(BUF, WAITN)                                                   \
        asm volatile("s_waitcnt vmcnt(" WAITN ")" ::: "memory");              \
        float CvB = 1.0f + *(const float*)((BUF) + 8192 + jj * 4);            \
        f32x4 acc0 = {0,0,0,0}, acc1 = {0,0,0,0};                             \
        f32x4 acc2 = {0,0,0,0}, acc3 = {0,0,0,0};                             \
        __builtin_amdgcn_s_setprio(1);                                        \
        _Pragma("unroll")                                                     \
        for (int s_ = 0; s_ < 8; ++s_) {                                      \
            short8v B_ = *(const short8v*)((BUF) + boff[s_]);                 \
            acc0 = __builtin_amdgcn_mfma_f32_16x16x32_bf16(Af[0][s_], B_, acc0, 0, 0, 0); \
            acc1 = __builtin_amdgcn_mfma_f32_16x16x32_bf16(Af[1][s_], B_, acc1, 0, 0, 0); \
            acc2 = __builtin_amdgcn_mfma_f32_16x16x32_bf16(Af[2][s_], B_, acc2, 0, 0, 0); \
            acc3 = __builtin_amdgcn_mfma_f32_16x16x32_bf16(Af[3][s_], B_, acc3, 0, 0, 0); \
        }                                                                     \
        __builtin_amdgcn_s_setprio(0);

    // MINC: phase-A tile -> register mins only (no LDS traffic, no atomics)
#define MINC(BUF)                                                             \
    {                                                                         \
        MFMADOT(BUF, "9")                                                     \
        _Pragma("unroll")                                                     \
        for (int r_ = 0; r_ < 4; ++r_) {                                      \
            amin[0][r_] = fminf(amin[0][r_], fmaf(-2.f, acc0[r_], CvB));      \
            amin[1][r_] = fminf(amin[1][r_], fmaf(-2.f, acc1[r_], CvB));      \
            amin[2][r_] = fminf(amin[2][r_], fmaf(-2.f, acc2[r_], CvB));      \
            amin[3][r_] = fminf(amin[3][r_], fmaf(-2.f, acc3[r_], CvB));      \
        }                                                                     \
    }

    // LOADTHR: refresh cached thresholds (staleness only over-collects)
#define LOADTHR                                                               \
    {                                                                         \
        _Pragma("unroll")                                                     \
        for (int t_ = 0; t_ < 4; ++t_)                                        \
            thrv[t_] = *(const f32x4*)&thrRow[t_ * 16 + g * 4];               \
    }

    // COMPUTE: MFMADOT + branchless mask + single compact slow path.
    // Scores written in-place into acc vectors; bit i (= t*4+r) of m_ set iff
    // score(t,r) <= thrv[t][r]. Slow path: ~2 iterations typical; score
    // recovered via 15-cndmask select tree (no dynamic register indexing).
#define COMPUTE(BUF, NT, WAITN)                                               \
    {                                                                         \
        MFMADOT(BUF, WAITN)                                                   \
        _Pragma("unroll")                                                     \
        for (int r_ = 0; r_ < 4; ++r_) {                                      \
            acc0[r_] = fmaf(-2.f, acc0[r_], CvB);                             \
            acc1[r_] = fmaf(-2.f, acc1[r_], CvB);                             \
            acc2[r_] = fmaf(-2.f, acc2[r_], CvB);                             \
            acc3[r_] = fmaf(-2.f, acc3[r_], CvB);                             \
        }                                                                     \
        unsigned m_ = 0;                                                      \
        _Pragma("unroll")                                                     \
        for (int r_ = 0; r_ < 4; ++r_) {                                      \
            m_ |= (acc0[r_] <= thrv[0][r_]) ? (1u << (0 + r_))  : 0u;         \
            m_ |= (acc1[r_] <= thrv[1][r_]) ? (1u << (4 + r_))  : 0u;         \
            m_ |= (acc2[r_] <= thrv[2][r_]) ? (1u << (8 + r_))  : 0u;         \
            m_ |= (acc3[r_] <= thrv[3][r_]) ? (1u << (12 + r_)) : 0u;         \
        }                                                                     \
        if (m_) {                                                             \
            int kc_ = (NT) * 16 + jj;                                         \
            do {                                                              \
                int i_ = __builtin_ctz(m_);                                   \
                m_ &= m_ - 1;                                                 \
                f32x4 va_ = (i_ & 8) ? ((i_ & 4) ? acc3 : acc2)               \
                                     : ((i_ & 4) ? acc1 : acc0);              \
                float sc_ = (i_ & 2) ? ((i_ & 1) ? va_[3] : va_[2])           \
                                     : ((i_ & 1) ? va_[1] : va_[0]);          \
                int row_ = ((i_ >> 2) << 4) + g * 4 + (i_ & 3);               \
                int p_ = atomicAdd(&cnt[row_], 1);                            \
                if (p_ < CAP) cand[row_][p_] = kc_;                           \
                if (sc_ + MARGIN < thrRow[row_])                              \
                    atomicMin((unsigned int*)&thrRow[row_],                   \
                              __float_as_uint(sc_ + MARGIN));                 \
            } while (m_);                                                     \
        }                                                                     \
    }

    // ---- phase A: tiles jv=0..7 per wave, min-only (512 codes block-wide) ----
    float amin[4][4];
    #pragma unroll
    for (int t = 0; t < 4; ++t)
        #pragma unroll
        for (int r = 0; r < 4; ++r) amin[t][r] = 3.4e38f;

    STAGE(b0, NTOF(0));
    STAGE(b1, NTOF(1));
    #pragma unroll 1
    for (int ja = 0; ja < 8; ja += 2) {
        MINC(b0)
        STAGE(b0, NTOF(ja + 2));      // ja=6 pre-stages NTOF(8) for phase B
        MINC(b1)
        STAGE(b1, NTOF(ja + 3));      // ja=6 pre-stages NTOF(9)
    }

    // seed thrRow = min-of-512 + MARGIN (reduce 16 lanes, atomicMin x 4 waves)
    #pragma unroll
    for (int t = 0; t < 4; ++t)
        #pragma unroll
        for (int r = 0; r < 4; ++r) {
            float v = amin[t][r];
            #pragma unroll
            for (int off = 1; off <= 8; off <<= 1)
                v = fminf(v, __shfl_xor(v, off, 16));
            if (jj == 0)
                atomicMin((unsigned int*)&thrRow[t * 16 + g * 4 + r],
                          __float_as_uint(v + MARGIN));
        }
    __syncthreads();   // thr visible to all waves (drains vmcnt; b0/b1 complete)

    // ---- phases B+C: tiles jv=8..63 (collect) then 64..71 (re-run A-tiles) ----
    f32x4 thrv[4];
    LOADTHR
    #pragma unroll 1
    for (int jv = 8; jv < 70; jv += 2) {
        COMPUTE(b0, NTOF(jv), "9");
        STAGE(b0, NTOF(jv + 2));
        COMPUTE(b1, NTOF(jv + 1), "9");
        STAGE(b1, NTOF(jv + 3));      // jv=68 stages NTOF(70)/NTOF(71)
        LOADTHR                       // refresh every 2 tiles
    }
    COMPUTE(b0, NTOF(70), "9");
    COMPUTE(b1, NTOF(71), "0");       // final: drain
    __syncthreads();                  // cand/cnt visible; ebuf dead after this

#undef NTOF
#undef STAGE
#undef MFMADOT
#undef MINC
#undef LOADTHR
#undef COMPUTE

    // ---- exact fp32 rescore of candidates (4 threads per row, 2-way ILP) ----
    const int crow = tid & 63;
    const int sub  = tid >> 6;
    unsigned long long best = ~0ULL;
    {
        int cc = cnt[crow];
        float rowA = A[rowBase + crow];
        const float* xsrow = x + (size_t)(rowBase + crow) * DIM;
        if (cc <= CAP) {
            int c = sub;
            for (; c + 4 < cc; c += 8) {
                unsigned long long pk = exact_pack2(emb, C, xsrow, rowA,
                                                   cand[crow][c], cand[crow][c + 4]);
                best = best < pk ? best : pk;
            }
            if (c < cc) {
                unsigned long long pk = exact_pack(emb, C, xsrow, rowA, cand[crow][c]);
                best = best < pk ? best : pk;
            }
        } else {
            // overflow fallback (rare): full exact row scan
            for (int k = sub; k < KCB; k += 8) {
                unsigned long long pk = exact_pack2(emb, C, xsrow, rowA, k, k + 4);
                best = best < pk ? best : pk;
            }
        }
    }
    sh.bestA[sub][crow] = best;          // ebuf/xstage dead; barrier above
    __syncthreads();
    if (tid < MROWS) {
        unsigned long long v0 = sh.bestA[0][tid], v1 = sh.bestA[1][tid];
        unsigned long long v2 = sh.bestA[2][tid], v3 = sh.bestA[3][tid];
        unsigned long long b = v0 < v1 ? v0 : v1;
        unsigned long long c2 = v2 < v3 ? v2 : v3;
        b = b < c2 ? b : c2;
        int idx = (int)(unsigned)(b & 0xFFFFFFFFull);
        sIdx[tid] = idx;
        out[1 + (size_t)N_TOK * DIM + rowBase + tid] = (float)idx;
    }
    __syncthreads();

    // ---- outputs: quantized gather (exact) + fp64 loss partial ----
    double lsum = 0.0;
    for (int row = 0; row < MROWS; ++row) {
        int idx = sIdx[row];
        float q  = emb[(size_t)idx * DIM + tid];
        float xv = x[(size_t)(rowBase + row) * DIM + tid];
        out[1 + (size_t)(rowBase + row) * DIM + tid] = q;
        double df = (double)q - (double)xv;
        lsum += df * df;
    }
    #pragma unroll
    for (int off = 1; off < 64; off <<= 1) lsum += __shfl_xor(lsum, off, 64);
    __syncthreads();
    if ((tid & 63) == 0) sRed[tid >> 6] = lsum;
    __syncthreads();
    if (tid == 0) atomicAdd(lossAcc, sRed[0] + sRed[1] + sRed[2] + sRed[3]);
}

// ---------------------------------------------------------------------------
// Legacy kernel (proven-passing), fallback if ws is too small.
__global__ __launch_bounds__(256, 2) void vq_np(
    const float* __restrict__ x, const float* __restrict__ emb,
    const float* __restrict__ A, const float* __restrict__ C,
    float* __restrict__ out, double* __restrict__ lossAcc)
{
    __shared__ float xs[MROWS][DIM];
    __shared__ float est[DC][ESD];
    __shared__ float sA[MROWS];
    __shared__ int   sIdx[MROWS];
    __shared__ double sRed[4];

    const int tid = threadIdx.x;
    const int c = tid & 31;
    const int r = tid >> 5;
    const int rowBase = blockIdx.x * MROWS;

    if (tid < MROWS) sA[tid] = A[rowBase + tid];

    #pragma unroll
    for (int p = 0; p < 16; ++p) {
        int flat = p * 256 + tid;
        int row = flat >> 6, d = (flat & 63) * 4;
        float4 v = *(const float4*)(x + (size_t)(rowBase + row) * DIM + d);
        *(float4*)&xs[row][d] = v;
    }

    float m1[8];
    int   i1[8];
    #pragma unroll
    for (int ri = 0; ri < 8; ++ri) { m1[ri] = 3.4e38f; i1[ri] = 0; }

    for (int kt = 0; kt < NKT; ++kt) {
        float acc[8][8];
        #pragma unroll
        for (int ri = 0; ri < 8; ++ri)
            #pragma unroll
            for (int kk = 0; kk < 8; ++kk) acc[ri][kk] = 0.f;

        for (int dc = 0; dc < NDC; ++dc) {
            const float* src = emb + (size_t)(kt * KT + tid) * DIM + dc * DC;
            float4 ea = *(const float4*)(src);
            float4 eb = *(const float4*)(src + 4);
            __syncthreads();
            est[0][tid] = ea.x; est[1][tid] = ea.y; est[2][tid] = ea.z; est[3][tid] = ea.w;
            est[4][tid] = eb.x; est[5][tid] = eb.y; est[6][tid] = eb.z; est[7][tid] = eb.w;
            __syncthreads();
            #pragma unroll
            for (int d4 = 0; d4 < 2; ++d4) {
                float4 xf[8];
                #pragma unroll
                for (int ri = 0; ri < 8; ++ri)
                    xf[ri] = *(const float4*)&xs[r * 8 + ri][dc * DC + d4 * 4];
                #pragma unroll
                for (int dd = 0; dd < 4; ++dd) {
                    float2 ev[4];
                    #pragma unroll
                    for (int j = 0; j < 4; ++j)
                        ev[j] = *(const float2*)&est[d4 * 4 + dd][2 * c + 64 * j];
                    #pragma unroll
                    for (int ri = 0; ri < 8; ++ri) {
                        float xv = (dd == 0) ? xf[ri].x : (dd == 1) ? xf[ri].y
                                 : (dd == 2) ? xf[ri].z : xf[ri].w;
                        #pragma unroll
                        for (int j = 0; j < 4; ++j) {
                            acc[ri][2 * j]     = fmaf(xv, ev[j].x, acc[ri][2 * j]);
                            acc[ri][2 * j + 1] = fmaf(xv, ev[j].y, acc[ri][2 * j + 1]);
                        }
                    }
                }
            }
        }
        #pragma unroll
        for (int j = 0; j < 4; ++j) {
            float2 Cv = *(const float2*)&C[kt * KT + 2 * c + 64 * j];
            #pragma unroll
            for (int p = 0; p < 2; ++p) {
                int kg = kt * KT + 2 * c + 64 * j + p;
                float Ck = (p == 0) ? Cv.x : Cv.y;
                #pragma unroll
                for (int ri = 0; ri < 8; ++ri) {
                    float tmp = sA[r * 8 + ri] - 2.0f * acc[ri][2 * j + p];
                    float s   = tmp + Ck;
                    if (s < m1[ri]) { m1[ri] = s; i1[ri] = kg; }
                }
            }
        }
    }

    #pragma unroll
    for (int ri = 0; ri < 8; ++ri) {
        float a = m1[ri]; int ja = i1[ri];
        #pragma unroll
        for (int off = 1; off <= 16; off <<= 1) {
            float b  = __shfl_xor(a, off, 64);
            int   jb = __shfl_xor(ja, off, 64);
            if (b < a || (b == a && jb < ja)) { a = b; ja = jb; }
        }
        if (c == 0) sIdx[r * 8 + ri] = ja;
    }
    __syncthreads();

    if (tid < MROWS) {
        out[1 + (size_t)N_TOK * DIM + rowBase + tid] = (float)sIdx[tid];
    }
    double lsum = 0.0;
    for (int row = 0; row < MROWS; ++row) {
        int idx = sIdx[row];
        float q  = emb[(size_t)idx * DIM + tid];
        float xv = xs[row][tid];
        out[1 + (size_t)(rowBase + row) * DIM + tid] = q;
        double df = (double)q - (double)xv;
        lsum += df * df;
    }
    #pragma unroll
    for (int off = 1; off < 64; off <<= 1) lsum += __shfl_xor(lsum, off, 64);
    __syncthreads();
    if ((tid & 63) == 0) sRed[tid >> 6] = lsum;
    __syncthreads();
    if (tid == 0) {
        atomicAdd(lossAcc, sRed[0] + sRed[1] + sRed[2] + sRed[3]);
    }
}

// ---------------------------------------------------------------------------
__global__ void finalize_kernel(const double* __restrict__ lossAcc, float* __restrict__ out) {
    out[0] = (float)(0.5 * (*lossAcc) / (double)((size_t)N_TOK * DIM));
}

extern "C" void kernel_launch(void* const* d_in, const int* in_sizes, int n_in,
                              void* d_out, int out_size, void* d_ws, size_t ws_size,
                              hipStream_t stream) {
    const float* x   = (const float*)d_in[0];   // [16,2048,256] fp32
    const float* emb = (const float*)d_in[1];   // [4096,256] fp32
    float* out = (float*)d_out;

    double* lossAcc = (double*)d_ws;
    float*  A       = (float*)((char*)d_ws + WS_A);
    float*  C       = (float*)((char*)d_ws + WS_C);
    unsigned char* etiles = (unsigned char*)((char*)d_ws + WS_E);

    const bool use_new = ws_size >= WS_NEED_NEW;

    hipMemsetAsync(d_ws, 0, 16, stream);
    xsq_np_kernel<<<N_TOK / 4, 256, 0, stream>>>(x, A);
    esq_np_kernel<<<KCB / 4, 256, 0, stream>>>(emb, C, use_new ? etiles : nullptr);
    if (use_new)
        vq_mfma<<<N_TOK / MROWS, 256, 0, stream>>>(x, emb, etiles, A, C, out, lossAcc);
    else
        vq_np<<<N_TOK / MROWS, 256, 0, stream>>>(x, emb, A, C, out, lossAcc);
    finalize_kernel<<<1, 1, 0, stream>>>(lossAcc, out);
}

// Round 11
// 253.210 us; speedup vs baseline: 43.5670x; 1.0205x over previous
//
#include <hip/hip_runtime.h>

#define N_TOK 32768
#define DIM   256
#define KCB   4096
#define MROWS 64           // rows per block
#define XSP   260          // padded xstage row stride (floats)
#define NTILE (KCB / 16)   // 256 code-tiles of 16 codes
#define TILE_B 8448        // 16*256*2 (bf16, swizzled) + 256 (C floats, 64B valid)
// ---- legacy-kernel tile params (fallback path) ----
#define KT    256
#define NKT   (KCB / KT)
#define DC    8
#define NDC   (DIM / DC)
#define ESD   258

// ws layout (bytes):
//   0      : double lossAcc (zeroed by 16B memset)
//   16     : float A[N_TOK]  -- used by FALLBACK path only (xsq kernel)
//   131088 : float C[KCB]    -- fp32 ||e_k||^2
//   147472 : etiles[256][8448] -- pre-swizzled bf16 code-tiles + appended C
#define WS_A 16
#define WS_C (16 + 4 * N_TOK)
#define WS_E (WS_C + 4 * KCB)
#define WS_NEED_NEW ((size_t)WS_E + (size_t)NTILE * TILE_B)

#define CAP    48          // candidate list capacity per row
#define MARGIN 1.5e-3f     // >= 2x worst-case bf16-approx score error (~5e-4 hard)
// Approx scores biased by +1.0f -> POSITIVE -> u32-bit atomicMin == float-min.
// r8: min-of-64 seed -> loose-seed straggler tail; phase A seeds from 512.
// r10: branchy vs branchless collection identical (~5.9K cyc/collect-tile) ->
// cost is pipeline/issue, not divergence. This round: split vmcnt (14/9),
// STAGE issued before the collect slow-path, xsq folded into the prologue.

typedef __attribute__((ext_vector_type(8))) short short8v;  // 8 x bf16 bits
typedef __attribute__((ext_vector_type(4))) float f32x4;

__device__ __forceinline__ unsigned short f2bf_rne(float f) {
    unsigned u = __float_as_uint(f);
    unsigned r = (u + 0x7FFFu + ((u >> 16) & 1u)) >> 16;
    return (unsigned short)r;
}

// async global->LDS staging helpers (size must be literal)
__device__ __forceinline__ void gld16(const void* g, void* l) {
    __builtin_amdgcn_global_load_lds(
        (const __attribute__((address_space(1))) unsigned int*)g,
        (__attribute__((address_space(3))) unsigned int*)l, 16, 0, 0);
}
__device__ __forceinline__ void gld4(const void* g, void* l) {
    __builtin_amdgcn_global_load_lds(
        (const __attribute__((address_space(1))) unsigned int*)g,
        (__attribute__((address_space(3))) unsigned int*)l, 4, 0, 0);
}

// ---------------------------------------------------------------------------
// Kernel A (FALLBACK ONLY): numpy-replica fp32 row sum-of-squares.
__global__ __launch_bounds__(256) void xsq_np_kernel(const float* __restrict__ x,
                                                     float* __restrict__ A) {
#pragma clang fp contract(off)
    __shared__ float xr[4][256];
    const int tid = threadIdx.x;
    const int w = tid >> 6, l = tid & 63;
    const int row = blockIdx.x * 4 + w;
    float4 v = *(const float4*)(x + (size_t)row * DIM + l * 4);
    xr[w][l * 4 + 0] = v.x; xr[w][l * 4 + 1] = v.y;
    xr[w][l * 4 + 2] = v.z; xr[w][l * 4 + 3] = v.w;
    __syncthreads();
    const float* t = xr[w];
    const int g = (l >> 4) & 1;
    const int j = l & 15;
    const int base = g * 128 + j;
    float t0 = t[base +   0] * t[base +   0];
    float t1 = t[base +  16] * t[base +  16];
    float t2 = t[base +  32] * t[base +  32];
    float t3 = t[base +  48] * t[base +  48];
    float t4 = t[base +  64] * t[base +  64];
    float t5 = t[base +  80] * t[base +  80];
    float t6 = t[base +  96] * t[base +  96];
    float t7 = t[base + 112] * t[base + 112];
    float p = ((t0 + t1) + (t2 + t3)) + ((t4 + t5) + (t6 + t7));
    p = p + __shfl_xor(p, 8, 64);
    p = p + __shfl_xor(p, 4, 64);
    p = p + __shfl_xor(p, 2, 64);
    p = p + __shfl_xor(p, 1, 64);
    float other = __shfl(p, 16, 64);
    if (l == 0) A[row] = p + other;
}

// ---------------------------------------------------------------------------
// Kernel B: C[k] exact; also emits PRE-SWIZZLED bf16 tiles + appended C.
// Rotation swizzle: 16B unit u stored at u ^ f(jj), f(jj)=((jj>>1)&3)|((jj&1)<<2).
__global__ void esq_np_kernel(const float* __restrict__ emb, float* __restrict__ C,
                              unsigned char* __restrict__ etiles) {
#pragma clang fp contract(off)
    int row  = blockIdx.x * 4 + (threadIdx.x >> 6);
    int lane = threadIdx.x & 63;
    float4 v = *(const float4*)(emb + (size_t)row * DIM + lane * 4);
    int tile = row >> 4, jj = row & 15;
    if (etiles) {
        ushort4 h;
        h.x = f2bf_rne(v.x); h.y = f2bf_rne(v.y);
        h.z = f2bf_rne(v.z); h.w = f2bf_rne(v.w);
        int f  = ((jj >> 1) & 3) | ((jj & 1) << 2);
        int u  = jj * 32 + (lane >> 1);      // 16B unit within tile
        int qs = u ^ f;                      // swizzled unit (stays in row: f<8<32)
        *(ushort4*)(etiles + (size_t)tile * TILE_B + qs * 16 + (lane & 1) * 8) = h;
    }
    float s0 = v.x * v.x, s1 = v.y * v.y, s2 = v.z * v.z, s3 = v.w * v.w;
    double qd = (double)s0 + (double)s1 + (double)s2 + (double)s3;
    #pragma unroll
    for (int off = 32; off; off >>= 1) qd += __shfl_xor(qd, off, 64);
    if (lane == 0) {
        float cf = (float)qd;
        C[row] = cf;
        if (etiles)
            *(float*)(etiles + (size_t)tile * TILE_B + 8192 + jj * 4) = cf;
    }
}

// ---------------------------------------------------------------------------
// Exact fp32 score, bit-identical arithmetic to the proven-passing kernel.
__device__ __forceinline__ unsigned long long exact_pack(
    const float* __restrict__ emb, const float* __restrict__ C,
    const float* __restrict__ xsrow, float rowA, int k)
{
    const float4* er = (const float4*)(emb + (size_t)k * DIM);
    float acc = 0.f;
    #pragma unroll 8
    for (int d4 = 0; d4 < DIM / 4; ++d4) {
        float4 ev = er[d4];
        float4 xv = *(const float4*)(xsrow + d4 * 4);
        acc = fmaf(xv.x, ev.x, acc);
        acc = fmaf(xv.y, ev.y, acc);
        acc = fmaf(xv.z, ev.z, acc);
        acc = fmaf(xv.w, ev.w, acc);
    }
    float tmp = rowA - 2.0f * acc;
    float sc  = tmp + C[k];
    // exact scores are squared distances (positive): bit pattern is monotone
    return ((unsigned long long)__float_as_uint(sc) << 32) | (unsigned)k;
}

// Two candidates interleaved (independent fmaf chains -> 2x ILP).
__device__ __forceinline__ unsigned long long exact_pack2(
    const float* __restrict__ emb, const float* __restrict__ C,
    const float* __restrict__ xsrow, float rowA, int k1, int k2)
{
    const float4* e1 = (const float4*)(emb + (size_t)k1 * DIM);
    const float4* e2 = (const float4*)(emb + (size_t)k2 * DIM);
    float a1 = 0.f, a2 = 0.f;
    #pragma unroll 8
    for (int d4 = 0; d4 < DIM / 4; ++d4) {
        float4 xv = *(const float4*)(xsrow + d4 * 4);
        float4 v1 = e1[d4];
        float4 v2 = e2[d4];
        a1 = fmaf(xv.x, v1.x, a1);  a2 = fmaf(xv.x, v2.x, a2);
        a1 = fmaf(xv.y, v1.y, a1);  a2 = fmaf(xv.y, v2.y, a2);
        a1 = fmaf(xv.z, v1.z, a1);  a2 = fmaf(xv.z, v2.z, a2);
        a1 = fmaf(xv.w, v1.w, a1);  a2 = fmaf(xv.w, v2.w, a2);
    }
    float s1 = (rowA - 2.0f * a1) + C[k1];
    float s2 = (rowA - 2.0f * a2) + C[k2];
    unsigned long long p1 = ((unsigned long long)__float_as_uint(s1) << 32) | (unsigned)k1;
    unsigned long long p2 = ((unsigned long long)__float_as_uint(s2) << 32) | (unsigned)k2;
    return p1 < p2 ? p1 : p2;
}

// ---------------------------------------------------------------------------
// Kernel C: single bf16-MFMA sweep, 3 phases (A: seed min-of-512; B: collect;
// C: re-run A-tiles vs final thr). ||x||^2 computed IN-KERNEL from the staged
// x-tile with numpy-replica arithmetic (contract off) -> sA[]; xsq kernel and
// the global A array are no longer used on this path. Split vmcnt (14/9) lets
// MFMA s=0..3 overlap the staging tail; STAGE issues before the collect slow
// path. Monotone thr via atomicMin on positive-biased score bits.
__global__ __launch_bounds__(256, 2) void vq_mfma(
    const float* __restrict__ x, const float* __restrict__ emb,
    const unsigned char* __restrict__ etiles,
    const float* __restrict__ C,
    float* __restrict__ out, double* __restrict__ lossAcc)
{
    __shared__ union {
        float xstage[MROWS][XSP];                 // 66560 B (prologue only)
        unsigned char ebuf[4][2][TILE_B];         // 67584 B (sweep: per-wave dbuf)
        unsigned long long bestA[4][MROWS];       // 2048 B (post-sweep only)
    } sh;
    __shared__ int    cand[MROWS][CAP];           // 12288
    __shared__ int    cnt[MROWS];
    __shared__ float  thrRow[MROWS];              // monotone threshold (atomicMin bits)
    __shared__ float  sA[MROWS];                  // in-kernel numpy-replica ||x||^2
    __shared__ int    sIdx[MROWS];
    __shared__ double sRed[4];

    const int tid = threadIdx.x;
    const int w   = tid >> 6;        // wave 0..3 (owns code-tiles j*4+w)
    const int l   = tid & 63;
    const int jj  = l & 15;          // MFMA col lane (code within tile)
    const int g   = l >> 4;          // MFMA k-group / D row group
    const int rowBase = blockIdx.x * MROWS;

    // ---- stage x tile into (padded) LDS ----
    #pragma unroll
    for (int p = 0; p < 16; ++p) {
        int flat = p * 256 + tid;
        int row = flat >> 6, d = (flat & 63) * 4;
        *(float4*)&sh.xstage[row][d] = *(const float4*)(x + (size_t)(rowBase + row) * DIM + d);
    }
    if (tid < MROWS) { cnt[tid] = 0; thrRow[tid] = 3.4e38f; }
    __syncthreads();

    // ---- in-kernel ||x||^2: numpy-replica bits (same exprs as xsq kernel) ----
    {
#pragma clang fp contract(off)
        const int gg = (l >> 4) & 1;
        const int jx = l & 15;
        const int base = gg * 128 + jx;
        #pragma unroll 1
        for (int rr = 0; rr < 16; ++rr) {
            const int row = w * 16 + rr;
            const float* t = &sh.xstage[row][0];
            float t0 = t[base +   0] * t[base +   0];
            float t1 = t[base +  16] * t[base +  16];
            float t2 = t[base +  32] * t[base +  32];
            float t3 = t[base +  48] * t[base +  48];
            float t4 = t[base +  64] * t[base +  64];
            float t5 = t[base +  80] * t[base +  80];
            float t6 = t[base +  96] * t[base +  96];
            float t7 = t[base + 112] * t[base + 112];
            float p = ((t0 + t1) + (t2 + t3)) + ((t4 + t5) + (t6 + t7));
            p = p + __shfl_xor(p, 8, 64);
            p = p + __shfl_xor(p, 4, 64);
            p = p + __shfl_xor(p, 2, 64);
            p = p + __shfl_xor(p, 1, 64);
            float other = __shfl(p, 16, 64);
            if (l == 0) sA[row] = p + other;
        }
    }

    // ---- build all A fragments: 4 row-tiles x 8 k-steps ----
    short8v Af[4][8];
    #pragma unroll
    for (int t = 0; t < 4; ++t)
        #pragma unroll
        for (int s = 0; s < 8; ++s) {
            const float* xp = &sh.xstage[t * 16 + jj][s * 32 + g * 8];
            float4 a = *(const float4*)xp;
            float4 b = *(const float4*)(xp + 4);
            short8v f;
            f[0] = (short)f2bf_rne(a.x); f[1] = (short)f2bf_rne(a.y);
            f[2] = (short)f2bf_rne(a.z); f[3] = (short)f2bf_rne(a.w);
            f[4] = (short)f2bf_rne(b.x); f[5] = (short)f2bf_rne(b.y);
            f[6] = (short)f2bf_rne(b.z); f[7] = (short)f2bf_rne(b.w);
            Af[t][s] = f;
        }
    __syncthreads();   // all waves done reading xstage before ebuf overwrite

    // swizzled per-lane B-frag byte offsets (constant over tiles)
    const int fsw = ((jj >> 1) & 3) | ((jj & 1) << 2);
    int boff[8];
    #pragma unroll
    for (int s = 0; s < 8; ++s)
        boff[s] = ((jj * 32 + s * 4 + g) ^ fsw) * 16;

    unsigned char* b0 = sh.ebuf[w][0];
    unsigned char* b1 = sh.ebuf[w][1];

    f32x4 acc0, acc1, acc2, acc3;
    float CvB;
    unsigned mRes;
    int kcRes;
    f32x4 thrv[4];

#define NTOF(JV) ((((JV) & 63) * 4) + w)

    // STAGE: 9 async global->LDS ops (8x gld16 then gld4) for tile NT
#define STAGE(BUF, NT)                                                        \
    {                                                                         \
        const unsigned char* src_ = etiles + (size_t)(NT) * TILE_B;           \
        _Pragma("unroll")                                                     \
        for (int j_ = 0; j_ < 8; ++j_)                                        \
            gld16(src_ + j_ * 1024 + l * 16, (BUF) + j_ * 1024);              \
        gld4(src_ + 8192 + l * 4, (BUF) + 8192);                              \
    }

    // MFMACORE: split waits -- W1 covers B0..B3 (MFMA s=0..3 overlap the
    // staging tail), W2 covers B4..B7 + the C-append. Sets acc0..3, CvB.
#define MFMACORE(BUF, W1, W2)                                                 \
        asm volatile("s_waitcnt vmcnt(" W1 ")" ::: "memory");                 \
        acc0 = (f32x4){0,0,0,0}; acc1 = (f32x4){0,0,0,0};                     \
        acc2 = (f32x4){0,0,0,0}; acc3 = (f32x4){0,0,0,0};                     \
        __builtin_amdgcn_s_setprio(1);                                        \
        _Pragma("unroll")                                                     \
        for (int s_ = 0; s_ < 4; ++s_) {                                      \
            short8v B_ = *(const short8v*)((BUF) + boff[s_]);                 \
            acc0 = __builtin_amdgcn_mfma_f32_16x16x32_bf16(Af[0][s_], B_, acc0, 0, 0, 0); \
            acc1 = __builtin_amdgcn_mfma_f32_16x16x32_bf16(Af[1][s_], B_, acc1, 0, 0, 0); \
            acc2 = __builtin_amdgcn_mfma_f32_16x16x32_bf16(Af[2][s_], B_, acc2, 0, 0, 0); \
            acc3 = __builtin_amdgcn_mfma_f32_16x16x32_bf16(Af[3][s_], B_, acc3, 0, 0, 0); \
        }                                                                     \
        asm volatile("s_waitcnt vmcnt(" W2 ")" ::: "memory");                 \
        _Pragma("unroll")                                                     \
        for (int s_ = 4; s_ < 8; ++s_) {                                      \
            short8v B_ = *(const short8v*)((BUF) + boff[s_]);                 \
            acc0 = __builtin_amdgcn_mfma_f32_16x16x32_bf16(Af[0][s_], B_, acc0, 0, 0, 0); \
            acc1 = __builtin_amdgcn_mfma_f32_16x16x32_bf16(Af[1][s_], B_, acc1, 0, 0, 0); \
            acc2 = __builtin_amdgcn_mfma_f32_16x16x32_bf16(Af[2][s_], B_, acc2, 0, 0, 0); \
            acc3 = __builtin_amdgcn_mfma_f32_16x16x32_bf16(Af[3][s_], B_, acc3, 0, 0, 0); \
        }                                                                     \
        __builtin_amdgcn_s_setprio(0);                                        \
        CvB = 1.0f + *(const float*)((BUF) + 8192 + jj * 4);

    // MINC: phase-A tile -> register mins only
#define MINC(BUF)                                                             \
    {                                                                         \
        MFMACORE(BUF, "14", "9")                                              \
        _Pragma("unroll")                                                     \
        for (int r_ = 0; r_ < 4; ++r_) {                                      \
            amin[0][r_] = fminf(amin[0][r_], fmaf(-2.f, acc0[r_], CvB));      \
            amin[1][r_] = fminf(amin[1][r_], fmaf(-2.f, acc1[r_], CvB));      \
            amin[2][r_] = fminf(amin[2][r_], fmaf(-2.f, acc2[r_], CvB));      \
            amin[3][r_] = fminf(amin[3][r_], fmaf(-2.f, acc3[r_], CvB));      \
        }                                                                     \
    }

#define LOADTHR                                                               \
    {                                                                         \
        _Pragma("unroll")                                                     \
        for (int t_ = 0; t_ < 4; ++t_)                                        \
            thrv[t_] = *(const f32x4*)&thrRow[t_ * 16 + g * 4];               \
    }

    // SCORES: MFMA + in-place biased scores + 16-bit mask (branchless)
#define SCORES(BUF, NT, W1, W2)                                               \
    {                                                                         \
        MFMACORE(BUF, W1, W2)                                                 \
        _Pragma("unroll")                                                     \
        for (int r_ = 0; r_ < 4; ++r_) {                                      \
            acc0[r_] = fmaf(-2.f, acc0[r_], CvB);                             \
            acc1[r_] = fmaf(-2.f, acc1[r_], CvB);                             \
            acc2[r_] = fmaf(-2.f, acc2[r_], CvB);                             \
            acc3[r_] = fmaf(-2.f, acc3[r_], CvB);                             \
        }                                                                     \
        mRes = 0;                                                             \
        _Pragma("unroll")                                                     \
        for (int r_ = 0; r_ < 4; ++r_) {                                      \
            mRes |= (acc0[r_] <= thrv[0][r_]) ? (1u << (0 + r_))  : 0u;       \
            mRes |= (acc1[r_] <= thrv[1][r_]) ? (1u << (4 + r_))  : 0u;       \
            mRes |= (acc2[r_] <= thrv[2][r_]) ? (1u << (8 + r_))  : 0u;       \
            mRes |= (acc3[r_] <= thrv[3][r_]) ? (1u << (12 + r_)) : 0u;       \
        }                                                                     \
        kcRes = (NT) * 16 + jj;                                               \
    }

    // COLLECT: compact slow path; unconditional monotone atomicMin tighten.
#define COLLECT()                                                             \
    if (mRes) {                                                               \
        unsigned mm_ = mRes;                                                  \
        do {                                                                  \
            int i_ = __builtin_ctz(mm_);                                      \
            mm_ &= mm_ - 1;                                                   \
            f32x4 va_ = (i_ & 8) ? ((i_ & 4) ? acc3 : acc2)                   \
                                 : ((i_ & 4) ? acc1 : acc0);                  \
            float sc_ = (i_ & 2) ? ((i_ & 1) ? va_[3] : va_[2])               \
                                 : ((i_ & 1) ? va_[1] : va_[0]);              \
            int row_ = ((i_ >> 2) << 4) + g * 4 + (i_ & 3);                   \
            int p_ = atomicAdd(&cnt[row_], 1);                                \
            if (p_ < CAP) cand[row_][p_] = kcRes;                             \
            atomicMin((unsigned int*)&thrRow[row_],                           \
                      __float_as_uint(sc_ + MARGIN));                         \
        } while (mm_);                                                        \
    }

    // ---- phase A: tiles jv=0..7 per wave, min-only (512 codes block-wide) ----
    float amin[4][4];
    #pragma unroll
    for (int t = 0; t < 4; ++t)
        #pragma unroll
        for (int r = 0; r < 4; ++r) amin[t][r] = 3.4e38f;

    STAGE(b0, NTOF(0));
    STAGE(b1, NTOF(1));
    #pragma unroll 1
    for (int ja = 0; ja < 8; ja += 2) {
        MINC(b0)
        STAGE(b0, NTOF(ja + 2));      // ja=6 pre-stages NTOF(8) for phase B
        MINC(b1)
        STAGE(b1, NTOF(ja + 3));      // ja=6 pre-stages NTOF(9)
    }

    // seed thrRow = min-of-512 + MARGIN (reduce 16 lanes, atomicMin x 4 waves)
    #pragma unroll
    for (int t = 0; t < 4; ++t)
        #pragma unroll
        for (int r = 0; r < 4; ++r) {
            float v = amin[t][r];
            #pragma unroll
            for (int off = 1; off <= 8; off <<= 1)
                v = fminf(v, __shfl_xor(v, off, 16));
            if (jj == 0)
                atomicMin((unsigned int*)&thrRow[t * 16 + g * 4 + r],
                          __float_as_uint(v + MARGIN));
        }
    __syncthreads();   // thr visible to all waves (drains vmcnt; b0/b1 complete)

    // ---- phases B+C: tiles jv=8..63 (collect) then 64..71 (re-run A-tiles) ----
    LOADTHR
    #pragma unroll 1
    for (int jv = 8; jv < 70; jv += 2) {
        SCORES(b0, NTOF(jv), "14", "9");
        STAGE(b0, NTOF(jv + 2));
        COLLECT()
        SCORES(b1, NTOF(jv + 1), "14", "9");
        STAGE(b1, NTOF(jv + 3));      // jv=68 stages NTOF(70)/NTOF(71)
        COLLECT()
        LOADTHR                       // refresh every 2 tiles
    }
    SCORES(b0, NTOF(70), "14", "9");
    COLLECT()
    SCORES(b1, NTOF(71), "5", "0");   // final: drain
    COLLECT()
    __syncthreads();                  // cand/cnt visible; ebuf dead after this

#undef NTOF
#undef STAGE
#undef MFMACORE
#undef MINC
#undef LOADTHR
#undef SCORES
#undef COLLECT

    // ---- exact fp32 rescore of candidates (4 threads per row, 2-way ILP) ----
    const int crow = tid & 63;
    const int sub  = tid >> 6;
    unsigned long long best = ~0ULL;
    {
        int cc = cnt[crow];
        float rowA = sA[crow];
        const float* xsrow = x + (size_t)(rowBase + crow) * DIM;
        if (cc <= CAP) {
            int c = sub;
            for (; c + 4 < cc; c += 8) {
                unsigned long long pk = exact_pack2(emb, C, xsrow, rowA,
                                                   cand[crow][c], cand[crow][c + 4]);
                best = best < pk ? best : pk;
            }
            if (c < cc) {
                unsigned long long pk = exact_pack(emb, C, xsrow, rowA, cand[crow][c]);
                best = best < pk ? best : pk;
            }
        } else {
            // overflow fallback (rare): full exact row scan
            for (int k = sub; k < KCB; k += 8) {
                unsigned long long pk = exact_pack2(emb, C, xsrow, rowA, k, k + 4);
                best = best < pk ? best : pk;
            }
        }
    }
    sh.bestA[sub][crow] = best;          // ebuf/xstage dead; barrier above
    __syncthreads();
    if (tid < MROWS) {
        unsigned long long v0 = sh.bestA[0][tid], v1 = sh.bestA[1][tid];
        unsigned long long v2 = sh.bestA[2][tid], v3 = sh.bestA[3][tid];
        unsigned long long b = v0 < v1 ? v0 : v1;
        unsigned long long c2 = v2 < v3 ? v2 : v3;
        b = b < c2 ? b : c2;
        int idx = (int)(unsigned)(b & 0xFFFFFFFFull);
        sIdx[tid] = idx;
        out[1 + (size_t)N_TOK * DIM + rowBase + tid] = (float)idx;
    }
    __syncthreads();

    // ---- outputs: quantized gather (exact) + fp64 loss partial ----
    double lsum = 0.0;
    for (int row = 0; row < MROWS; ++row) {
        int idx = sIdx[row];
        float q  = emb[(size_t)idx * DIM + tid];
        float xv = x[(size_t)(rowBase + row) * DIM + tid];
        out[1 + (size_t)(rowBase + row) * DIM + tid] = q;
        double df = (double)q - (double)xv;
        lsum += df * df;
    }
    #pragma unroll
    for (int off = 1; off < 64; off <<= 1) lsum += __shfl_xor(lsum, off, 64);
    __syncthreads();
    if ((tid & 63) == 0) sRed[tid >> 6] = lsum;
    __syncthreads();
    if (tid == 0) atomicAdd(lossAcc, sRed[0] + sRed[1] + sRed[2] + sRed[3]);
}

// ---------------------------------------------------------------------------
// Legacy kernel (proven-passing), fallback if ws is too small.
__global__ __launch_bounds__(256, 2) void vq_np(
    const float* __restrict__ x, const float* __restrict__ emb,
    const float* __restrict__ A, const float* __restrict__ C,
    float* __restrict__ out, double* __restrict__ lossAcc)
{
    __shared__ float xs[MROWS][DIM];
    __shared__ float est[DC][ESD];
    __shared__ float sA[MROWS];
    __shared__ int   sIdx[MROWS];
    __shared__ double sRed[4];

    const int tid = threadIdx.x;
    const int c = tid & 31;
    const int r = tid >> 5;
    const int rowBase = blockIdx.x * MROWS;

    if (tid < MROWS) sA[tid] = A[rowBase + tid];

    #pragma unroll
    for (int p = 0; p < 16; ++p) {
        int flat = p * 256 + tid;
        int row = flat >> 6, d = (flat & 63) * 4;
        float4 v = *(const float4*)(x + (size_t)(rowBase + row) * DIM + d);
        *(float4*)&xs[row][d] = v;
    }

    float m1[8];
    int   i1[8];
    #pragma unroll
    for (int ri = 0; ri < 8; ++ri) { m1[ri] = 3.4e38f; i1[ri] = 0; }

    for (int kt = 0; kt < NKT; ++kt) {
        float acc[8][8];
        #pragma unroll
        for (int ri = 0; ri < 8; ++ri)
            #pragma unroll
            for (int kk = 0; kk < 8; ++kk) acc[ri][kk] = 0.f;

        for (int dc = 0; dc < NDC; ++dc) {
            const float* src = emb + (size_t)(kt * KT + tid) * DIM + dc * DC;
            float4 ea = *(const float4*)(src);
            float4 eb = *(const float4*)(src + 4);
            __syncthreads();
            est[0][tid] = ea.x; est[1][tid] = ea.y; est[2][tid] = ea.z; est[3][tid] = ea.w;
            est[4][tid] = eb.x; est[5][tid] = eb.y; est[6][tid] = eb.z; est[7][tid] = eb.w;
            __syncthreads();
            #pragma unroll
            for (int d4 = 0; d4 < 2; ++d4) {
                float4 xf[8];
                #pragma unroll
                for (int ri = 0; ri < 8; ++ri)
                    xf[ri] = *(const float4*)&xs[r * 8 + ri][dc * DC + d4 * 4];
                #pragma unroll
                for (int dd = 0; dd < 4; ++dd) {
                    float2 ev[4];
                    #pragma unroll
                    for (int j = 0; j < 4; ++j)
                        ev[j] = *(const float2*)&est[d4 * 4 + dd][2 * c + 64 * j];
                    #pragma unroll
                    for (int ri = 0; ri < 8; ++ri) {
                        float xv = (dd == 0) ? xf[ri].x : (dd == 1) ? xf[ri].y
                                 : (dd == 2) ? xf[ri].z : xf[ri].w;
                        #pragma unroll
                        for (int j = 0; j < 4; ++j) {
                            acc[ri][2 * j]     = fmaf(xv, ev[j].x, acc[ri][2 * j]);
                            acc[ri][2 * j + 1] = fmaf(xv, ev[j].y, acc[ri][2 * j + 1]);
                        }
                    }
                }
            }
        }
        #pragma unroll
        for (int j = 0; j < 4; ++j) {
            float2 Cv = *(const float2*)&C[kt * KT + 2 * c + 64 * j];
            #pragma unroll
            for (int p = 0; p < 2; ++p) {
                int kg = kt * KT + 2 * c + 64 * j + p;
                float Ck = (p == 0) ? Cv.x : Cv.y;
                #pragma unroll
                for (int ri = 0; ri < 8; ++ri) {
                    float tmp = sA[r * 8 + ri] - 2.0f * acc[ri][2 * j + p];
                    float s   = tmp + Ck;
                    if (s < m1[ri]) { m1[ri] = s; i1[ri] = kg; }
                }
            }
        }
    }

    #pragma unroll
    for (int ri = 0; ri < 8; ++ri) {
        float a = m1[ri]; int ja = i1[ri];
        #pragma unroll
        for (int off = 1; off <= 16; off <<= 1) {
            float b  = __shfl_xor(a, off, 64);
            int   jb = __shfl_xor(ja, off, 64);
            if (b < a || (b == a && jb < ja)) { a = b; ja = jb; }
        }
        if (c == 0) sIdx[r * 8 + ri] = ja;
    }
    __syncthreads();

    if (tid < MROWS) {
        out[1 + (size_t)N_TOK * DIM + rowBase + tid] = (float)sIdx[tid];
    }
    double lsum = 0.0;
    for (int row = 0; row < MROWS; ++row) {
        int idx = sIdx[row];
        float q  = emb[(size_t)idx * DIM + tid];
        float xv = xs[row][tid];
        out[1 + (size_t)(rowBase + row) * DIM + tid] = q;
        double df = (double)q - (double)xv;
        lsum += df * df;
    }
    #pragma unroll
    for (int off = 1; off < 64; off <<= 1) lsum += __shfl_xor(lsum, off, 64);
    __syncthreads();
    if ((tid & 63) == 0) sRed[tid >> 6] = lsum;
    __syncthreads();
    if (tid == 0) {
        atomicAdd(lossAcc, sRed[0] + sRed[1] + sRed[2] + sRed[3]);
    }
}

// ---------------------------------------------------------------------------
__global__ void finalize_kernel(const double* __restrict__ lossAcc, float* __restrict__ out) {
    out[0] = (float)(0.5 * (*lossAcc) / (double)((size_t)N_TOK * DIM));
}

extern "C" void kernel_launch(void* const* d_in, const int* in_sizes, int n_in,
                              void* d_out, int out_size, void* d_ws, size_t ws_size,
                              hipStream_t stream) {
    const float* x   = (const float*)d_in[0];   // [16,2048,256] fp32
    const float* emb = (const float*)d_in[1];   // [4096,256] fp32
    float* out = (float*)d_out;

    double* lossAcc = (double*)d_ws;
    float*  A       = (float*)((char*)d_ws + WS_A);
    float*  C       = (float*)((char*)d_ws + WS_C);
    unsigned char* etiles = (unsigned char*)((char*)d_ws + WS_E);

    const bool use_new = ws_size >= WS_NEED_NEW;

    hipMemsetAsync(d_ws, 0, 16, stream);
    if (use_new) {
        esq_np_kernel<<<KCB / 4, 256, 0, stream>>>(emb, C, etiles);
        vq_mfma<<<N_TOK / MROWS, 256, 0, stream>>>(x, emb, etiles, C, out, lossAcc);
    } else {
        xsq_np_kernel<<<N_TOK / 4, 256, 0, stream>>>(x, A);
        esq_np_kernel<<<KCB / 4, 256, 0, stream>>>(emb, C, nullptr);
        vq_np<<<N_TOK / MROWS, 256, 0, stream>>>(x, emb, A, C, out, lossAcc);
    }
    finalize_kernel<<<1, 1, 0, stream>>>(lossAcc, out);
}